// Round 2
// baseline (5905.378 us; speedup 1.0000x reference)
//
#include <hip/hip_runtime.h>
#include <math.h>

#define BATCH 2
#define SEQ   2048
#define EMB   1024
#define NHEAD 16
#define DHEAD 64

typedef unsigned int  uint;
typedef unsigned short ushort;

// ---------------- positional encoding table ----------------
__global__ void pos_init(float* __restrict__ pos) {
    int s = blockIdx.x;
    int d = threadIdx.x;              // 0..63
    int i = d >> 1;
    float expo  = (float)(2 * i) / (float)DHEAD;
    float scale = 1.0f / (powf(10000.0f, expo) + 1.1920928955078125e-07f);
    float ang   = (float)s * scale;
    pos[s * DHEAD + d] = (d & 1) ? cosf(ang) : sinf(ang);
}

// ---------------- fp32 tiled GEMM: C[M,N] = A[M,K] @ B[K,N] (+pos) ----------
#define BM 64
#define BN 64
#define BK 16

__global__ __launch_bounds__(256) void gemm_f32(
    const float* __restrict__ A, const float* __restrict__ B,
    float* __restrict__ C, const float* __restrict__ pos, int addpos,
    int M, int N, int K) {
    __shared__ float As[BK][BM];   // transposed: As[k][m]
    __shared__ float Bs[BK][BN];   // Bs[k][n]

    const int tid = threadIdx.x;
    const int bm  = blockIdx.x * BM;
    const int bn  = blockIdx.y * BN;
    const int tx  = tid & 15;          // n-group 0..15
    const int ty  = tid >> 4;          // m-group 0..15
    const int arow = tid >> 2;         // 0..63
    const int acol = (tid & 3) << 2;   // 0,4,8,12
    const int brow = tid >> 4;         // 0..15
    const int bcol = (tid & 15) << 2;  // 0..60

    float acc[4][4] = {{0.f}};

    const float* Aptr = A + (size_t)(bm + arow) * K + acol;
    const float* Bptr = B + (size_t)brow * N + bn + bcol;

    for (int k0 = 0; k0 < K; k0 += BK) {
        float4 av = *(const float4*)(Aptr + k0);
        float4 bv = *(const float4*)(Bptr + (size_t)k0 * N);
        __syncthreads();
        As[acol + 0][arow] = av.x;
        As[acol + 1][arow] = av.y;
        As[acol + 2][arow] = av.z;
        As[acol + 3][arow] = av.w;
        *(float4*)&Bs[brow][bcol] = bv;
        __syncthreads();
#pragma unroll
        for (int kk = 0; kk < BK; ++kk) {
            float4 a = *(const float4*)&As[kk][ty << 2];
            float4 b = *(const float4*)&Bs[kk][tx << 2];
            float aa[4] = {a.x, a.y, a.z, a.w};
            float bb[4] = {b.x, b.y, b.z, b.w};
#pragma unroll
            for (int i = 0; i < 4; ++i)
#pragma unroll
                for (int j = 0; j < 4; ++j)
                    acc[i][j] += aa[i] * bb[j];
        }
    }

#pragma unroll
    for (int i = 0; i < 4; ++i) {
        int m = bm + (ty << 2) + i;
        int n = bn + (tx << 2);
        float4 v = make_float4(acc[i][0], acc[i][1], acc[i][2], acc[i][3]);
        if (addpos) {
            int s = m & (SEQ - 1);
            int d = n & (DHEAD - 1);   // multiple of 4
            float4 p = *(const float4*)&pos[s * DHEAD + d];
            v.x += p.x; v.y += p.y; v.z += p.z; v.w += p.w;
        }
        *(float4*)&C[(size_t)m * N + n] = v;
    }
}

// ---------------- bf16 pack/unpack helpers ----------------
__device__ __forceinline__ uint pack_bf16x2(float a, float b) {
    union { float f; uint u; } x, y;
    x.f = a; y.f = b;
    uint ua = x.u + 0x7fffu + ((x.u >> 16) & 1u);   // RNE
    uint ub = y.u + 0x7fffu + ((y.u >> 16) & 1u);
    return (ua >> 16) | (ub & 0xffff0000u);
}
__device__ __forceinline__ float unpack_lo(uint u) {
    union { uint u; float f; } v; v.u = u << 16; return v.f;
}
__device__ __forceinline__ float unpack_hi(uint u) {
    union { uint u; float f; } v; v.u = u & 0xffff0000u; return v.f;
}

// ---------------- K-split flash attention (partial pass) ----------
#define QT 128
#define KT 32

// Opart layout: bf16 [c][bh][row][64]; ML layout: float2 [c][bh][row]
__global__ __launch_bounds__(QT) void attn_split(
    const float* __restrict__ Q, const float* __restrict__ Kg,
    const float* __restrict__ V, ushort* __restrict__ Opart,
    float* __restrict__ ML, int chunk) {
    const int q0 = blockIdx.x * QT;
    const int k0 = blockIdx.y * chunk;
    if (k0 >= q0 + QT) return;                   // fully-masked chunk

    __shared__ float Ks[KT][DHEAD];
    __shared__ float Vs[KT][DHEAD];

    const int t    = threadIdx.x;
    const int bh   = blockIdx.z;
    const int b    = bh >> 4;
    const int h    = bh & 15;
    const int qrow = q0 + t;
    const size_t base = (size_t)b * SEQ * EMB + (size_t)h * DHEAD;

    float4 q4[16], o4[16];
#pragma unroll
    for (int i = 0; i < 16; ++i) {
        q4[i] = *(const float4*)&Q[base + (size_t)qrow * EMB + i * 4];
        o4[i] = make_float4(0.f, 0.f, 0.f, 0.f);
    }
    float m_i = -3.0e38f, l_i = 0.0f;
    const float scale = 0.03125f;  // 1024^-0.5

    const int kend = min(k0 + chunk, q0 + QT);
    for (int kt = k0; kt < kend; kt += KT) {
        __syncthreads();
#pragma unroll
        for (int i = 0; i < 4; ++i) {
            int idx = t + i * QT;            // 0..511
            int r = idx >> 4;
            int c = (idx & 15) << 2;
            *(float4*)&Ks[r][c] = *(const float4*)&Kg[base + (size_t)(kt + r) * EMB + c];
            *(float4*)&Vs[r][c] = *(const float4*)&V [base + (size_t)(kt + r) * EMB + c];
        }
        __syncthreads();

        float sv[KT];
        float mt = m_i;
#pragma unroll
        for (int j = 0; j < KT; ++j) {
            const float4* kr = (const float4*)Ks[j];
            float dot = 0.f;
#pragma unroll
            for (int dd = 0; dd < 16; ++dd) {
                float4 kv = kr[dd];
                dot += q4[dd].x * kv.x + q4[dd].y * kv.y +
                       q4[dd].z * kv.z + q4[dd].w * kv.w;
            }
            sv[j] = (kt + j <= qrow) ? dot * scale : -3.0e38f;
            mt = fmaxf(mt, sv[j]);
        }

        float corr = __expf(m_i - mt);
        l_i *= corr;
#pragma unroll
        for (int i = 0; i < 16; ++i) {
            o4[i].x *= corr; o4[i].y *= corr; o4[i].z *= corr; o4[i].w *= corr;
        }
#pragma unroll
        for (int j = 0; j < KT; ++j) {
            float p = __expf(sv[j] - mt);
            l_i += p;
            const float4* vr = (const float4*)Vs[j];
#pragma unroll
            for (int dd = 0; dd < 16; ++dd) {
                float4 vv = vr[dd];
                o4[dd].x += p * vv.x; o4[dd].y += p * vv.y;
                o4[dd].z += p * vv.z; o4[dd].w += p * vv.w;
            }
        }
        m_i = mt;
    }

    // write partial (unnormalized o in bf16, m/l in fp32)
    const size_t prow = ((size_t)blockIdx.y * 32 + bh) * SEQ + qrow;
    uint4* op = (uint4*)(Opart + prow * DHEAD);
#pragma unroll
    for (int i = 0; i < 8; ++i) {
        float4 a = o4[2 * i], bb = o4[2 * i + 1];
        uint4 u;
        u.x = pack_bf16x2(a.x,  a.y);
        u.y = pack_bf16x2(a.z,  a.w);
        u.z = pack_bf16x2(bb.x, bb.y);
        u.w = pack_bf16x2(bb.z, bb.w);
        op[i] = u;
    }
    *(float2*)&ML[prow * 2] = make_float2(m_i, l_i);
}

// ---------------- combine pass ----------------
__global__ __launch_bounds__(256) void attn_combine(
    const ushort* __restrict__ Opart, const float* __restrict__ ML,
    float* __restrict__ O, int cshift) {
    const int gid = blockIdx.x * 256 + threadIdx.x;   // 0 .. 32*2048-1
    const int bh  = gid >> 11;
    const int row = gid & (SEQ - 1);
    const int b   = bh >> 4;
    const int h   = bh & 15;
    const int cmax = row >> cshift;                    // inclusive

    float mv[8], lv[8];
    float M = -3.0e38f;
#pragma unroll
    for (int c = 0; c < 8; ++c) {
        if (c <= cmax) {
            const size_t prow = ((size_t)c * 32 + bh) * SEQ + row;
            float2 ml = *(const float2*)&ML[prow * 2];
            mv[c] = ml.x; lv[c] = ml.y;
            M = fmaxf(M, ml.x);
        }
    }
    float L = 0.f, w[8];
#pragma unroll
    for (int c = 0; c < 8; ++c) {
        if (c <= cmax) {
            w[c] = __expf(mv[c] - M);
            L += lv[c] * w[c];
        }
    }
    const float inv = 1.0f / L;

    float acc[64];
#pragma unroll
    for (int d = 0; d < 64; ++d) acc[d] = 0.f;

#pragma unroll
    for (int c = 0; c < 8; ++c) {
        if (c <= cmax) {
            const size_t prow = ((size_t)c * 32 + bh) * SEQ + row;
            const uint4* op = (const uint4*)(Opart + prow * DHEAD);
            float wc = w[c];
#pragma unroll
            for (int i = 0; i < 8; ++i) {
                uint4 u = op[i];
                acc[i * 8 + 0] += wc * unpack_lo(u.x);
                acc[i * 8 + 1] += wc * unpack_hi(u.x);
                acc[i * 8 + 2] += wc * unpack_lo(u.y);
                acc[i * 8 + 3] += wc * unpack_hi(u.y);
                acc[i * 8 + 4] += wc * unpack_lo(u.z);
                acc[i * 8 + 5] += wc * unpack_hi(u.z);
                acc[i * 8 + 6] += wc * unpack_lo(u.w);
                acc[i * 8 + 7] += wc * unpack_hi(u.w);
            }
        }
    }
    const size_t obase = (size_t)b * SEQ * EMB + (size_t)row * EMB + (size_t)h * DHEAD;
#pragma unroll
    for (int i = 0; i < 16; ++i) {
        float4 v = make_float4(acc[i*4+0]*inv, acc[i*4+1]*inv, acc[i*4+2]*inv, acc[i*4+3]*inv);
        *(float4*)&O[obase + i * 4] = v;
    }
}

// ---------------- single-pass fallback (ws too small) ---------
__global__ __launch_bounds__(QT) void attn_fwd(
    const float* __restrict__ Q, const float* __restrict__ Kg,
    const float* __restrict__ V, float* __restrict__ O) {
    __shared__ float Ks[KT][DHEAD];
    __shared__ float Vs[KT][DHEAD];

    const int t    = threadIdx.x;
    const int q0   = blockIdx.x * QT;
    const int bh   = blockIdx.y;
    const int b    = bh >> 4;
    const int h    = bh & 15;
    const int qrow = q0 + t;
    const size_t base = (size_t)b * SEQ * EMB + (size_t)h * DHEAD;

    float4 q4[16], o4[16];
#pragma unroll
    for (int i = 0; i < 16; ++i) {
        q4[i] = *(const float4*)&Q[base + (size_t)qrow * EMB + i * 4];
        o4[i] = make_float4(0.f, 0.f, 0.f, 0.f);
    }
    float m_i = -3.0e38f, l_i = 0.0f;
    const float scale = 0.03125f;

    const int kend = q0 + QT;
    for (int k0 = 0; k0 < kend; k0 += KT) {
        __syncthreads();
#pragma unroll
        for (int i = 0; i < 4; ++i) {
            int idx = t + i * QT;
            int r = idx >> 4;
            int c = (idx & 15) << 2;
            *(float4*)&Ks[r][c] = *(const float4*)&Kg[base + (size_t)(k0 + r) * EMB + c];
            *(float4*)&Vs[r][c] = *(const float4*)&V [base + (size_t)(k0 + r) * EMB + c];
        }
        __syncthreads();

        float sv[KT];
        float mt = m_i;
#pragma unroll
        for (int j = 0; j < KT; ++j) {
            const float4* kr = (const float4*)Ks[j];
            float dot = 0.f;
#pragma unroll
            for (int dd = 0; dd < 16; ++dd) {
                float4 kv = kr[dd];
                dot += q4[dd].x * kv.x + q4[dd].y * kv.y +
                       q4[dd].z * kv.z + q4[dd].w * kv.w;
            }
            sv[j] = (k0 + j <= qrow) ? dot * scale : -3.0e38f;
            mt = fmaxf(mt, sv[j]);
        }
        float corr = __expf(m_i - mt);
        l_i *= corr;
#pragma unroll
        for (int i = 0; i < 16; ++i) {
            o4[i].x *= corr; o4[i].y *= corr; o4[i].z *= corr; o4[i].w *= corr;
        }
#pragma unroll
        for (int j = 0; j < KT; ++j) {
            float p = __expf(sv[j] - mt);
            l_i += p;
            const float4* vr = (const float4*)Vs[j];
#pragma unroll
            for (int dd = 0; dd < 16; ++dd) {
                float4 vv = vr[dd];
                o4[dd].x += p * vv.x; o4[dd].y += p * vv.y;
                o4[dd].z += p * vv.z; o4[dd].w += p * vv.w;
            }
        }
        m_i = mt;
    }
    float inv = 1.0f / l_i;
#pragma unroll
    for (int i = 0; i < 16; ++i) {
        float4 v = o4[i];
        v.x *= inv; v.y *= inv; v.z *= inv; v.w *= inv;
        *(float4*)&O[base + (size_t)qrow * EMB + i * 4] = v;
    }
}

// ---------------- launch ----------------
extern "C" void kernel_launch(void* const* d_in, const int* in_sizes, int n_in,
                              void* d_out, int out_size, void* d_ws, size_t ws_size,
                              hipStream_t stream) {
    const float* x  = (const float*)d_in[0];
    const float* Wq = (const float*)d_in[1];
    const float* Wk = (const float*)d_in[2];
    const float* Wv = (const float*)d_in[3];
    const float* Wo = (const float*)d_in[4];
    float* out = (float*)d_out;

    float* ws  = (float*)d_ws;
    float* pos = ws;                          // S*64 floats
    float* Qb  = pos + SEQ * DHEAD;
    float* Kb  = Qb + (size_t)BATCH * SEQ * EMB;
    float* Vb  = Kb + (size_t)BATCH * SEQ * EMB;
    float* AO  = Vb + (size_t)BATCH * SEQ * EMB;
    float* wend = AO + (size_t)BATCH * SEQ * EMB;   // end of base region

    const size_t base_bytes = (size_t)(wend - ws) * 4;
    // per-split: ML (32*2048 float2) + Opart (32*2048*64 bf16)
    const size_t ml_floats_per  = (size_t)32 * SEQ * 2;
    const size_t op_bytes_per   = (size_t)32 * SEQ * DHEAD * 2;
    const size_t split_bytes_per = ml_floats_per * 4 + op_bytes_per;

    int nsplit = 0;
    for (int ns = 8; ns >= 1; ns >>= 1) {
        if (base_bytes + (size_t)ns * split_bytes_per <= ws_size) { nsplit = ns; break; }
    }

    const int M = BATCH * SEQ, N = EMB, K = EMB;

    pos_init<<<SEQ, DHEAD, 0, stream>>>(pos);

    dim3 g(M / BM, N / BN), blk(256);
    gemm_f32<<<g, blk, 0, stream>>>(x,  Wq, Qb, pos, 1, M, N, K);
    gemm_f32<<<g, blk, 0, stream>>>(x,  Wk, Kb, pos, 1, M, N, K);
    gemm_f32<<<g, blk, 0, stream>>>(x,  Wv, Vb, pos, 0, M, N, K);

    if (nsplit > 0) {
        float*  ML    = wend;
        ushort* Opart = (ushort*)(wend + (size_t)nsplit * ml_floats_per);
        int chunk  = SEQ / nsplit;
        int cshift = 31 - __builtin_clz(chunk);
        attn_split<<<dim3(SEQ / QT, nsplit, BATCH * NHEAD), QT, 0, stream>>>(
            Qb, Kb, Vb, Opart, ML, chunk);
        attn_combine<<<(BATCH * NHEAD * SEQ) / 256, 256, 0, stream>>>(
            Opart, ML, AO, cshift);
    } else {
        attn_fwd<<<dim3(SEQ / QT, BATCH * NHEAD), QT, 0, stream>>>(Qb, Kb, Vb, AO);
    }

    gemm_f32<<<g, blk, 0, stream>>>(AO, Wo, out, pos, 0, M, N, K);
}

// Round 3
// 1544.582 us; speedup vs baseline: 3.8233x; 3.8233x over previous
//
#include <hip/hip_runtime.h>
#include <math.h>

#define BATCH 2
#define SEQ   2048
#define EMB   1024
#define NHEAD 16
#define DHEAD 64
#define MROWS (BATCH*SEQ)

typedef unsigned int  uint;
typedef unsigned short ushort;
typedef __attribute__((ext_vector_type(8))) short short8;
typedef __attribute__((ext_vector_type(4))) float f32x4;

// ---------------- positional encoding table ----------------
__global__ void pos_init(float* __restrict__ pos) {
    int s = blockIdx.x;
    int d = threadIdx.x;              // 0..63
    int i = d >> 1;
    float expo  = (float)(2 * i) / (float)DHEAD;
    float scale = 1.0f / (powf(10000.0f, expo) + 1.1920928955078125e-07f);
    float ang   = (float)s * scale;
    pos[s * DHEAD + d] = (d & 1) ? cosf(ang) : sinf(ang);
}

// ---------------- bf16 helpers ----------------
__device__ __forceinline__ uint pack_bf16x2(float a, float b) {
    union { float f; uint u; } x, y;
    x.f = a; y.f = b;
    uint ua = x.u + 0x7fffu + ((x.u >> 16) & 1u);   // RNE
    uint ub = y.u + 0x7fffu + ((y.u >> 16) & 1u);
    return (ua >> 16) | (ub & 0xffff0000u);
}
__device__ __forceinline__ ushort bf16_1(float a) {
    union { float f; uint u; } x; x.f = a;
    return (ushort)((x.u + 0x7fffu + ((x.u >> 16) & 1u)) >> 16);
}
__device__ __forceinline__ float unpack_lo(uint u) {
    union { uint u; float f; } v; v.u = u << 16; return v.f;
}
__device__ __forceinline__ float unpack_hi(uint u) {
    union { uint u; float f; } v; v.u = u & 0xffff0000u; return v.f;
}

// ---------------- fp32 -> bf16 (rowmajor, no transpose) ----------------
__global__ __launch_bounds__(256) void cvt_bf16(
    const float* __restrict__ in, ushort* __restrict__ out, int n2) {
    int gid = blockIdx.x * 256 + threadIdx.x;
    if (gid < n2) {
        float2 v = ((const float2*)in)[gid];
        ((uint*)out)[gid] = pack_bf16x2(v.x, v.y);
    }
}

// ---------------- W[K][N] fp32 -> Wt[N][K] bf16 (transpose) ----------------
__global__ __launch_bounds__(256) void wt_bf16(
    const float* __restrict__ W, ushort* __restrict__ Wt) {
    __shared__ float tile[32][33];
    const int c0 = blockIdx.x * 32;   // n-tile
    const int r0 = blockIdx.y * 32;   // k-tile
    const int tx = threadIdx.x & 31;
    const int ty = threadIdx.x >> 5;  // 0..7
#pragma unroll
    for (int i = 0; i < 4; ++i)
        tile[ty + i * 8][tx] = W[(size_t)(r0 + ty + i * 8) * EMB + c0 + tx];
    __syncthreads();
#pragma unroll
    for (int i = 0; i < 4; ++i)
        Wt[(size_t)(c0 + ty + i * 8) * EMB + r0 + tx] = bf16_1(tile[tx][ty + i * 8]);
}

// ---------------- bf16 MFMA GEMM: C[M,N] = A[M,K] @ Bt[N,K]^T (+pos) -------
// tile 128x64, BK=32, 256 threads = 4 waves (each 64m x 32n of 16x16x32 MFMAs)
#define GBM 128
#define GBN 64
#define GBK 32

__global__ __launch_bounds__(256) void gemm_mfma(
    const ushort* __restrict__ A, const ushort* __restrict__ Bt,
    float* __restrict__ C, const float* __restrict__ pos, int addpos,
    int N, int K) {
    __shared__ ushort As[GBM * GBK];   // [m][k]
    __shared__ ushort Bs[GBN * GBK];   // [n][k]

    const int t    = threadIdx.x;
    const int bm   = blockIdx.x * GBM;
    const int bn   = blockIdx.y * GBN;
    const int lane = t & 63;
    const int w    = t >> 6;
    const int quad = lane >> 4;
    const int l15  = lane & 15;
    const int wm   = (w & 1) * 64;
    const int wn   = (w >> 1) * 32;

    const int srow = t >> 2;          // staging row 0..63
    const int spart = (t & 3) * 8;    // k-offset in ushorts

    f32x4 acc[4][2];
#pragma unroll
    for (int mi = 0; mi < 4; ++mi)
#pragma unroll
        for (int ni = 0; ni < 2; ++ni)
            acc[mi][ni] = (f32x4){0.f, 0.f, 0.f, 0.f};

    const ushort* Ap0 = A  + (size_t)(bm + srow) * K + spart;
    const ushort* Ap1 = A  + (size_t)(bm + 64 + srow) * K + spart;
    const ushort* Bp  = Bt + (size_t)(bn + srow) * K + spart;

    for (int k0 = 0; k0 < K; k0 += GBK) {
        uint4 a0 = *(const uint4*)(Ap0 + k0);
        uint4 a1 = *(const uint4*)(Ap1 + k0);
        uint4 b0 = *(const uint4*)(Bp  + k0);
        __syncthreads();
        *(uint4*)&As[srow * GBK + spart]        = a0;
        *(uint4*)&As[(64 + srow) * GBK + spart] = a1;
        *(uint4*)&Bs[srow * GBK + spart]        = b0;
        __syncthreads();

        short8 af[4], bfr[2];
#pragma unroll
        for (int mi = 0; mi < 4; ++mi)
            af[mi] = *(const short8*)&As[(wm + mi * 16 + l15) * GBK + quad * 8];
#pragma unroll
        for (int ni = 0; ni < 2; ++ni)
            bfr[ni] = *(const short8*)&Bs[(wn + ni * 16 + l15) * GBK + quad * 8];
#pragma unroll
        for (int mi = 0; mi < 4; ++mi)
#pragma unroll
            for (int ni = 0; ni < 2; ++ni)
                acc[mi][ni] = __builtin_amdgcn_mfma_f32_16x16x32_bf16(
                    af[mi], bfr[ni], acc[mi][ni], 0, 0, 0);
    }

#pragma unroll
    for (int mi = 0; mi < 4; ++mi) {
#pragma unroll
        for (int r = 0; r < 4; ++r) {
            int row = bm + wm + mi * 16 + quad * 4 + r;
            int s   = row & (SEQ - 1);
#pragma unroll
            for (int ni = 0; ni < 2; ++ni) {
                int col = bn + wn + ni * 16 + l15;
                float v = acc[mi][ni][r];
                if (addpos) v += pos[s * DHEAD + (col & (DHEAD - 1))];
                C[(size_t)row * N + col] = v;
            }
        }
    }
}

// ---------------- fp32 tiled GEMM fallback ----------------
#define BM 64
#define BN 64
#define BK 16

__global__ __launch_bounds__(256) void gemm_f32(
    const float* __restrict__ A, const float* __restrict__ B,
    float* __restrict__ C, const float* __restrict__ pos, int addpos,
    int M, int N, int K) {
    __shared__ float As[BK][BM];
    __shared__ float Bs[BK][BN];
    const int tid = threadIdx.x;
    const int bm  = blockIdx.x * BM;
    const int bn  = blockIdx.y * BN;
    const int tx  = tid & 15;
    const int ty  = tid >> 4;
    const int arow = tid >> 2;
    const int acol = (tid & 3) << 2;
    const int brow = tid >> 4;
    const int bcol = (tid & 15) << 2;
    float acc[4][4] = {{0.f}};
    const float* Aptr = A + (size_t)(bm + arow) * K + acol;
    const float* Bptr = B + (size_t)brow * N + bn + bcol;
    for (int k0 = 0; k0 < K; k0 += BK) {
        float4 av = *(const float4*)(Aptr + k0);
        float4 bv = *(const float4*)(Bptr + (size_t)k0 * N);
        __syncthreads();
        As[acol + 0][arow] = av.x;
        As[acol + 1][arow] = av.y;
        As[acol + 2][arow] = av.z;
        As[acol + 3][arow] = av.w;
        *(float4*)&Bs[brow][bcol] = bv;
        __syncthreads();
#pragma unroll
        for (int kk = 0; kk < BK; ++kk) {
            float4 a = *(const float4*)&As[kk][ty << 2];
            float4 b = *(const float4*)&Bs[kk][tx << 2];
            float aa[4] = {a.x, a.y, a.z, a.w};
            float bb[4] = {b.x, b.y, b.z, b.w};
#pragma unroll
            for (int i = 0; i < 4; ++i)
#pragma unroll
                for (int j = 0; j < 4; ++j)
                    acc[i][j] += aa[i] * bb[j];
        }
    }
#pragma unroll
    for (int i = 0; i < 4; ++i) {
        int m = bm + (ty << 2) + i;
        int n = bn + (tx << 2);
        float4 v = make_float4(acc[i][0], acc[i][1], acc[i][2], acc[i][3]);
        if (addpos) {
            int s = m & (SEQ - 1);
            int d = n & (DHEAD - 1);
            float4 p = *(const float4*)&pos[s * DHEAD + d];
            v.x += p.x; v.y += p.y; v.z += p.z; v.w += p.w;
        }
        *(float4*)&C[(size_t)m * N + n] = v;
    }
}

// ---------------- K-split attention, 4 threads per q-row ----------------
#define AQT 64
#define AKT 32

__global__ __launch_bounds__(256) void attn_split4(
    const float* __restrict__ Q, const float* __restrict__ Kg,
    const float* __restrict__ V, ushort* __restrict__ Opart,
    float* __restrict__ ML, int chunk) {
    const int q0 = blockIdx.x * AQT;
    const int k0 = blockIdx.y * chunk;
    if (k0 >= q0 + AQT) return;          // fully-masked chunk

    __shared__ float Ks[AKT][DHEAD];
    __shared__ float Vs[AKT][DHEAD];

    const int t  = threadIdx.x;
    const int rl = t >> 2;               // local row 0..63
    const int sl = t & 3;                // dim-slice 0..3 (16 dims each)
    const int bh = blockIdx.z;
    const int b  = bh >> 4;
    const int h  = bh & 15;
    const int qrow = q0 + rl;
    const size_t base = (size_t)b * SEQ * EMB + (size_t)h * DHEAD;

    float4 q4[4], o4[4];
    const float* qp = Q + base + (size_t)qrow * EMB + sl * 16;
#pragma unroll
    for (int i = 0; i < 4; ++i) {
        q4[i] = *(const float4*)(qp + i * 4);
        o4[i] = make_float4(0.f, 0.f, 0.f, 0.f);
    }
    float m_i = -3.0e38f, l_i = 0.0f;
    const float scale = 0.03125f;        // 1024^-0.5

    const int kend = min(k0 + chunk, q0 + AQT);
    for (int kt = k0; kt < kend; kt += AKT) {
        __syncthreads();
#pragma unroll
        for (int i = 0; i < 2; ++i) {
            int idx = t + i * 256;       // 0..511
            int r = idx >> 4;
            int c = (idx & 15) << 2;
            *(float4*)&Ks[r][c] = *(const float4*)&Kg[base + (size_t)(kt + r) * EMB + c];
            *(float4*)&Vs[r][c] = *(const float4*)&V [base + (size_t)(kt + r) * EMB + c];
        }
        __syncthreads();

        float sv[AKT];
        float mt = m_i;
#pragma unroll
        for (int j = 0; j < AKT; ++j) {
            const float4* kr = (const float4*)&Ks[j][sl * 16];
            float dot = 0.f;
#pragma unroll
            for (int i = 0; i < 4; ++i) {
                float4 kv = kr[i];
                dot += q4[i].x * kv.x + q4[i].y * kv.y +
                       q4[i].z * kv.z + q4[i].w * kv.w;
            }
            dot += __shfl_xor(dot, 1, 64);
            dot += __shfl_xor(dot, 2, 64);
            sv[j] = (kt + j <= qrow) ? dot * scale : -3.0e38f;
            mt = fmaxf(mt, sv[j]);
        }

        float corr = __expf(m_i - mt);
        l_i *= corr;
#pragma unroll
        for (int i = 0; i < 4; ++i) {
            o4[i].x *= corr; o4[i].y *= corr; o4[i].z *= corr; o4[i].w *= corr;
        }
#pragma unroll
        for (int j = 0; j < AKT; ++j) {
            float p = __expf(sv[j] - mt);
            l_i += p;
            const float4* vr = (const float4*)&Vs[j][sl * 16];
#pragma unroll
            for (int i = 0; i < 4; ++i) {
                float4 vv = vr[i];
                o4[i].x += p * vv.x; o4[i].y += p * vv.y;
                o4[i].z += p * vv.z; o4[i].w += p * vv.w;
            }
        }
        m_i = mt;
    }

    const size_t prow = ((size_t)blockIdx.y * 32 + bh) * SEQ + qrow;
    uint4* op = (uint4*)(Opart + prow * DHEAD + sl * 16);
    uint4 u0, u1;
    u0.x = pack_bf16x2(o4[0].x, o4[0].y);
    u0.y = pack_bf16x2(o4[0].z, o4[0].w);
    u0.z = pack_bf16x2(o4[1].x, o4[1].y);
    u0.w = pack_bf16x2(o4[1].z, o4[1].w);
    u1.x = pack_bf16x2(o4[2].x, o4[2].y);
    u1.y = pack_bf16x2(o4[2].z, o4[2].w);
    u1.z = pack_bf16x2(o4[3].x, o4[3].y);
    u1.w = pack_bf16x2(o4[3].z, o4[3].w);
    op[0] = u0; op[1] = u1;
    if (sl == 0) *(float2*)&ML[prow * 2] = make_float2(m_i, l_i);
}

// ---------------- combine pass ----------------
__global__ __launch_bounds__(256) void attn_combine(
    const ushort* __restrict__ Opart, const float* __restrict__ ML,
    float* __restrict__ O, int cshift) {
    const int gid = blockIdx.x * 256 + threadIdx.x;
    const int bh  = gid >> 11;
    const int row = gid & (SEQ - 1);
    const int b   = bh >> 4;
    const int h   = bh & 15;
    const int cmax = row >> cshift;

    float mv[8], lv[8];
    float M = -3.0e38f;
#pragma unroll
    for (int c = 0; c < 8; ++c) {
        if (c <= cmax) {
            const size_t prow = ((size_t)c * 32 + bh) * SEQ + row;
            float2 ml = *(const float2*)&ML[prow * 2];
            mv[c] = ml.x; lv[c] = ml.y;
            M = fmaxf(M, ml.x);
        }
    }
    float L = 0.f, w[8];
#pragma unroll
    for (int c = 0; c < 8; ++c) {
        if (c <= cmax) {
            w[c] = __expf(mv[c] - M);
            L += lv[c] * w[c];
        }
    }
    const float inv = 1.0f / L;

    float acc[64];
#pragma unroll
    for (int d = 0; d < 64; ++d) acc[d] = 0.f;

#pragma unroll
    for (int c = 0; c < 8; ++c) {
        if (c <= cmax) {
            const size_t prow = ((size_t)c * 32 + bh) * SEQ + row;
            const uint4* op = (const uint4*)(Opart + prow * DHEAD);
            float wc = w[c];
#pragma unroll
            for (int i = 0; i < 8; ++i) {
                uint4 u = op[i];
                acc[i * 8 + 0] += wc * unpack_lo(u.x);
                acc[i * 8 + 1] += wc * unpack_hi(u.x);
                acc[i * 8 + 2] += wc * unpack_lo(u.y);
                acc[i * 8 + 3] += wc * unpack_hi(u.y);
                acc[i * 8 + 4] += wc * unpack_lo(u.z);
                acc[i * 8 + 5] += wc * unpack_hi(u.z);
                acc[i * 8 + 6] += wc * unpack_lo(u.w);
                acc[i * 8 + 7] += wc * unpack_hi(u.w);
            }
        }
    }
    const size_t obase = (size_t)b * SEQ * EMB + (size_t)row * EMB + (size_t)h * DHEAD;
#pragma unroll
    for (int i = 0; i < 16; ++i) {
        float4 v = make_float4(acc[i*4+0]*inv, acc[i*4+1]*inv, acc[i*4+2]*inv, acc[i*4+3]*inv);
        *(float4*)&O[obase + i * 4] = v;
    }
}

// ---------------- single-pass fallback ----------------
#define QT 128
#define KT 32
__global__ __launch_bounds__(QT) void attn_fwd(
    const float* __restrict__ Q, const float* __restrict__ Kg,
    const float* __restrict__ V, float* __restrict__ O) {
    __shared__ float Ks[KT][DHEAD];
    __shared__ float Vs[KT][DHEAD];
    const int t    = threadIdx.x;
    const int q0   = blockIdx.x * QT;
    const int bh   = blockIdx.y;
    const int b    = bh >> 4;
    const int h    = bh & 15;
    const int qrow = q0 + t;
    const size_t base = (size_t)b * SEQ * EMB + (size_t)h * DHEAD;
    float4 q4[16], o4[16];
#pragma unroll
    for (int i = 0; i < 16; ++i) {
        q4[i] = *(const float4*)&Q[base + (size_t)qrow * EMB + i * 4];
        o4[i] = make_float4(0.f, 0.f, 0.f, 0.f);
    }
    float m_i = -3.0e38f, l_i = 0.0f;
    const float scale = 0.03125f;
    const int kend = q0 + QT;
    for (int k0 = 0; k0 < kend; k0 += KT) {
        __syncthreads();
#pragma unroll
        for (int i = 0; i < 4; ++i) {
            int idx = t + i * QT;
            int r = idx >> 4;
            int c = (idx & 15) << 2;
            *(float4*)&Ks[r][c] = *(const float4*)&Kg[base + (size_t)(k0 + r) * EMB + c];
            *(float4*)&Vs[r][c] = *(const float4*)&V [base + (size_t)(k0 + r) * EMB + c];
        }
        __syncthreads();
        float sv[KT];
        float mt = m_i;
#pragma unroll
        for (int j = 0; j < KT; ++j) {
            const float4* kr = (const float4*)Ks[j];
            float dot = 0.f;
#pragma unroll
            for (int dd = 0; dd < 16; ++dd) {
                float4 kv = kr[dd];
                dot += q4[dd].x * kv.x + q4[dd].y * kv.y +
                       q4[dd].z * kv.z + q4[dd].w * kv.w;
            }
            sv[j] = (k0 + j <= qrow) ? dot * scale : -3.0e38f;
            mt = fmaxf(mt, sv[j]);
        }
        float corr = __expf(m_i - mt);
        l_i *= corr;
#pragma unroll
        for (int i = 0; i < 16; ++i) {
            o4[i].x *= corr; o4[i].y *= corr; o4[i].z *= corr; o4[i].w *= corr;
        }
#pragma unroll
        for (int j = 0; j < KT; ++j) {
            float p = __expf(sv[j] - mt);
            l_i += p;
            const float4* vr = (const float4*)Vs[j];
#pragma unroll
            for (int dd = 0; dd < 16; ++dd) {
                float4 vv = vr[dd];
                o4[dd].x += p * vv.x; o4[dd].y += p * vv.y;
                o4[dd].z += p * vv.z; o4[dd].w += p * vv.w;
            }
        }
        m_i = mt;
    }
    float inv = 1.0f / l_i;
#pragma unroll
    for (int i = 0; i < 16; ++i) {
        float4 v = o4[i];
        v.x *= inv; v.y *= inv; v.z *= inv; v.w *= inv;
        *(float4*)&O[base + (size_t)qrow * EMB + i * 4] = v;
    }
}

// ---------------- launch ----------------
extern "C" void kernel_launch(void* const* d_in, const int* in_sizes, int n_in,
                              void* d_out, int out_size, void* d_ws, size_t ws_size,
                              hipStream_t stream) {
    const float* x  = (const float*)d_in[0];
    const float* Wq = (const float*)d_in[1];
    const float* Wk = (const float*)d_in[2];
    const float* Wv = (const float*)d_in[3];
    const float* Wo = (const float*)d_in[4];
    float* out = (float*)d_out;

    char* ws = (char*)d_ws;
    size_t off = 0;
    float* pos = (float*)(ws + off); off += (size_t)SEQ * DHEAD * 4;
    float* Qb  = (float*)(ws + off); off += (size_t)MROWS * EMB * 4;
    float* Kb  = (float*)(ws + off); off += (size_t)MROWS * EMB * 4;
    float* Vb  = (float*)(ws + off); off += (size_t)MROWS * EMB * 4;
    float* AO  = (float*)(ws + off); off += (size_t)MROWS * EMB * 4;
    const size_t base_end = off;

    // bf16 region
    ushort* xb  = (ushort*)(ws + off); off += (size_t)MROWS * EMB * 2;
    ushort* Wqt = (ushort*)(ws + off); off += (size_t)EMB * EMB * 2;
    ushort* Wkt = (ushort*)(ws + off); off += (size_t)EMB * EMB * 2;
    ushort* Wvt = (ushort*)(ws + off); off += (size_t)EMB * EMB * 2;
    ushort* Wot = (ushort*)(ws + off); off += (size_t)EMB * EMB * 2;
    ushort* AOb = (ushort*)(ws + off); off += (size_t)MROWS * EMB * 2;
    const size_t bf16_end = off;
    const bool use_bf16 = bf16_end <= ws_size;

    const size_t split_base = use_bf16 ? bf16_end : base_end;
    const size_t ml_bytes_per = (size_t)32 * SEQ * 2 * 4;
    const size_t op_bytes_per = (size_t)32 * SEQ * DHEAD * 2;
    int nsplit = 0;
    for (int ns = 8; ns >= 1; ns >>= 1) {
        if (split_base + (size_t)ns * (ml_bytes_per + op_bytes_per) <= ws_size) {
            nsplit = ns; break;
        }
    }

    const int M = MROWS, N = EMB, K = EMB;

    pos_init<<<SEQ, DHEAD, 0, stream>>>(pos);

    if (use_bf16) {
        const int n2 = MROWS * EMB / 2;
        cvt_bf16<<<n2 / 256, 256, 0, stream>>>(x, xb, n2);
        dim3 wtg(EMB / 32, EMB / 32);
        wt_bf16<<<wtg, 256, 0, stream>>>(Wq, Wqt);
        wt_bf16<<<wtg, 256, 0, stream>>>(Wk, Wkt);
        wt_bf16<<<wtg, 256, 0, stream>>>(Wv, Wvt);
        wt_bf16<<<wtg, 256, 0, stream>>>(Wo, Wot);
        dim3 gg(M / GBM, N / GBN);
        gemm_mfma<<<gg, 256, 0, stream>>>(xb, Wqt, Qb, pos, 1, N, K);
        gemm_mfma<<<gg, 256, 0, stream>>>(xb, Wkt, Kb, pos, 1, N, K);
        gemm_mfma<<<gg, 256, 0, stream>>>(xb, Wvt, Vb, pos, 0, N, K);
    } else {
        dim3 g(M / BM, N / BN);
        gemm_f32<<<g, 256, 0, stream>>>(x, Wq, Qb, pos, 1, M, N, K);
        gemm_f32<<<g, 256, 0, stream>>>(x, Wk, Kb, pos, 1, M, N, K);
        gemm_f32<<<g, 256, 0, stream>>>(x, Wv, Vb, pos, 0, M, N, K);
    }

    if (nsplit > 0) {
        float*  ML    = (float*)(ws + split_base);
        ushort* Opart = (ushort*)(ws + split_base + (size_t)nsplit * ml_bytes_per);
        int chunk  = SEQ / nsplit;
        int cshift = 31 - __builtin_clz(chunk);
        attn_split4<<<dim3(SEQ / AQT, nsplit, BATCH * NHEAD), 256, 0, stream>>>(
            Qb, Kb, Vb, Opart, ML, chunk);
        attn_combine<<<(BATCH * NHEAD * SEQ) / 256, 256, 0, stream>>>(
            Opart, ML, AO, cshift);
    } else {
        attn_fwd<<<dim3(SEQ / QT, BATCH * NHEAD), QT, 0, stream>>>(Qb, Kb, Vb, AO);
    }

    if (use_bf16) {
        const int n2 = MROWS * EMB / 2;
        cvt_bf16<<<n2 / 256, 256, 0, stream>>>(AO, AOb, n2);
        dim3 gg(M / GBM, N / GBN);
        gemm_mfma<<<gg, 256, 0, stream>>>(AOb, Wot, out, pos, 0, N, K);
    } else {
        dim3 g(M / BM, N / BN);
        gemm_f32<<<g, 256, 0, stream>>>(AO, Wo, out, pos, 0, M, N, K);
    }
}

// Round 4
// 290.492 us; speedup vs baseline: 20.3289x; 5.3171x over previous
//
#include <hip/hip_runtime.h>
#include <math.h>

#define BATCH 2
#define SEQ   2048
#define EMB   1024
#define NHEAD 16
#define DHEAD 64
#define MROWS (BATCH*SEQ)

typedef unsigned int  uint;
typedef unsigned short ushort;
typedef __attribute__((ext_vector_type(8))) short short8;
typedef __attribute__((ext_vector_type(4))) float f32x4;

// ---------------- positional encoding table ----------------
__global__ void pos_init(float* __restrict__ pos) {
    int s = blockIdx.x;
    int d = threadIdx.x;              // 0..63
    int i = d >> 1;
    float expo  = (float)(2 * i) / (float)DHEAD;
    float scale = 1.0f / (powf(10000.0f, expo) + 1.1920928955078125e-07f);
    float ang   = (float)s * scale;
    pos[s * DHEAD + d] = (d & 1) ? cosf(ang) : sinf(ang);
}

// ---------------- bf16 helpers ----------------
__device__ __forceinline__ uint pack_bf16x2(float a, float b) {
    union { float f; uint u; } x, y;
    x.f = a; y.f = b;
    uint ua = x.u + 0x7fffu + ((x.u >> 16) & 1u);   // RNE
    uint ub = y.u + 0x7fffu + ((y.u >> 16) & 1u);
    return (ua >> 16) | (ub & 0xffff0000u);
}
__device__ __forceinline__ ushort bf16_1(float a) {
    union { float f; uint u; } x; x.f = a;
    return (ushort)((x.u + 0x7fffu + ((x.u >> 16) & 1u)) >> 16);
}

// ---------------- fp32 -> bf16 (rowmajor) ----------------
__global__ __launch_bounds__(256) void cvt_bf16(
    const float* __restrict__ in, ushort* __restrict__ out, int n2) {
    int gid = blockIdx.x * 256 + threadIdx.x;
    if (gid < n2) {
        float2 v = ((const float2*)in)[gid];
        ((uint*)out)[gid] = pack_bf16x2(v.x, v.y);
    }
}

// ---------------- W[K][N] fp32 -> Wt[N][K] bf16 (transpose) ----------------
__global__ __launch_bounds__(256) void wt_bf16(
    const float* __restrict__ W, ushort* __restrict__ Wt) {
    __shared__ float tile[32][33];
    const int c0 = blockIdx.x * 32;   // n-tile
    const int r0 = blockIdx.y * 32;   // k-tile
    const int tx = threadIdx.x & 31;
    const int ty = threadIdx.x >> 5;  // 0..7
#pragma unroll
    for (int i = 0; i < 4; ++i)
        tile[ty + i * 8][tx] = W[(size_t)(r0 + ty + i * 8) * EMB + c0 + tx];
    __syncthreads();
#pragma unroll
    for (int i = 0; i < 4; ++i)
        Wt[(size_t)(c0 + ty + i * 8) * EMB + r0 + tx] = bf16_1(tile[tx][ty + i * 8]);
}

// ---- bf16 [token][EMB] -> Vt bf16 [bh][64][SEQ] (per-head transpose) ------
__global__ __launch_bounds__(256) void vt_tr(
    const ushort* __restrict__ V, ushort* __restrict__ Vt) {
    __shared__ ushort tile[64][72];
    const int s0 = blockIdx.x * 64;
    const int bh = blockIdx.y;
    const int b  = bh >> 4, h = bh & 15;
    const int t  = threadIdx.x;
    const int r  = t >> 2;             // 0..63
    const int c  = (t & 3) * 16;       // 0,16,32,48
    const ushort* src = V + (size_t)(b * SEQ + s0 + r) * EMB + h * 64 + c;
    *(uint4*)&tile[r][c]     = *(const uint4*)src;
    *(uint4*)&tile[r][c + 8] = *(const uint4*)(src + 8);
    __syncthreads();
    // out: d = r, s range = s0+c .. +16 ; Vt[bh][d][s] = tile[s-s0][d]
    uint ov[8];
#pragma unroll
    for (int i = 0; i < 8; ++i) {
        uint lo = tile[c + 2 * i][r];
        uint hi = tile[c + 2 * i + 1][r];
        ov[i] = lo | (hi << 16);
    }
    ushort* dst = Vt + ((size_t)bh * 64 + r) * SEQ + s0 + c;
    *(uint4*)dst       = *(uint4*)&ov[0];
    *(uint4*)(dst + 8) = *(uint4*)&ov[4];
}

// ---------------- bf16 MFMA GEMM: C[M,N] = A[M,K] @ Bt[N,K]^T (+pos) -------
#define GBM 128
#define GBN 64
#define GBK 32

__global__ __launch_bounds__(256) void gemm_mfma(
    const ushort* __restrict__ A, const ushort* __restrict__ Bt,
    void* __restrict__ Cv, const float* __restrict__ pos, int addpos,
    int out_bf16, int N, int K) {
    __shared__ ushort As[GBM * GBK];   // [m][k]
    __shared__ ushort Bs[GBN * GBK];   // [n][k]

    const int t    = threadIdx.x;
    const int bm   = blockIdx.x * GBM;
    const int bn   = blockIdx.y * GBN;
    const int lane = t & 63;
    const int w    = t >> 6;
    const int quad = lane >> 4;
    const int l15  = lane & 15;
    const int wm   = (w & 1) * 64;
    const int wn   = (w >> 1) * 32;

    const int srow  = t >> 2;
    const int spart = (t & 3) * 8;

    f32x4 acc[4][2];
#pragma unroll
    for (int mi = 0; mi < 4; ++mi)
#pragma unroll
        for (int ni = 0; ni < 2; ++ni)
            acc[mi][ni] = (f32x4){0.f, 0.f, 0.f, 0.f};

    const ushort* Ap0 = A  + (size_t)(bm + srow) * K + spart;
    const ushort* Ap1 = A  + (size_t)(bm + 64 + srow) * K + spart;
    const ushort* Bp  = Bt + (size_t)(bn + srow) * K + spart;

    for (int k0 = 0; k0 < K; k0 += GBK) {
        uint4 a0 = *(const uint4*)(Ap0 + k0);
        uint4 a1 = *(const uint4*)(Ap1 + k0);
        uint4 b0 = *(const uint4*)(Bp  + k0);
        __syncthreads();
        *(uint4*)&As[srow * GBK + spart]        = a0;
        *(uint4*)&As[(64 + srow) * GBK + spart] = a1;
        *(uint4*)&Bs[srow * GBK + spart]        = b0;
        __syncthreads();

        short8 af[4], bfr[2];
#pragma unroll
        for (int mi = 0; mi < 4; ++mi)
            af[mi] = *(const short8*)&As[(wm + mi * 16 + l15) * GBK + quad * 8];
#pragma unroll
        for (int ni = 0; ni < 2; ++ni)
            bfr[ni] = *(const short8*)&Bs[(wn + ni * 16 + l15) * GBK + quad * 8];
#pragma unroll
        for (int mi = 0; mi < 4; ++mi)
#pragma unroll
            for (int ni = 0; ni < 2; ++ni)
                acc[mi][ni] = __builtin_amdgcn_mfma_f32_16x16x32_bf16(
                    af[mi], bfr[ni], acc[mi][ni], 0, 0, 0);
    }

#pragma unroll
    for (int mi = 0; mi < 4; ++mi) {
#pragma unroll
        for (int r = 0; r < 4; ++r) {
            int row = bm + wm + mi * 16 + quad * 4 + r;
            int s   = row & (SEQ - 1);
#pragma unroll
            for (int ni = 0; ni < 2; ++ni) {
                int col = bn + wn + ni * 16 + l15;
                float v = acc[mi][ni][r];
                if (addpos) v += pos[s * DHEAD + (col & (DHEAD - 1))];
                if (out_bf16) ((ushort*)Cv)[(size_t)row * N + col] = bf16_1(v);
                else          ((float*) Cv)[(size_t)row * N + col] = v;
            }
        }
    }
}

// ---------------- MFMA flash attention (causal), bf16 in/out ----------------
// block: 64 q-rows x one (b,h); 4 waves; wave owns 16 rows.
#define LDP 72   // padded LDS row stride in ushorts

__global__ __launch_bounds__(256) void attn_mfma(
    const ushort* __restrict__ Qb, const ushort* __restrict__ Kb,
    const ushort* __restrict__ Vt, ushort* __restrict__ AOb) {
    __shared__ ushort Qs[64 * LDP];
    __shared__ ushort Ks[64 * LDP];
    __shared__ ushort Vs[64 * LDP];
    __shared__ ushort Ps[64 * LDP];

    const int qt   = (blockIdx.x + blockIdx.y) & 31;   // swizzle for balance
    const int bh   = blockIdx.y;
    const int b    = bh >> 4, h = bh & 15;
    const int t    = threadIdx.x;
    const int lane = t & 63, w = t >> 6;
    const int quad = lane >> 4, l15 = lane & 15;
    const int wrow = w * 16;

    const int sr = t >> 2;            // staging row 0..63
    const int sc = (t & 3) * 16;      // 0,16,32,48
    const size_t qkbase = (size_t)b * SEQ * EMB + (size_t)h * DHEAD;

    // stage Q tile once
    {
        const ushort* src = Qb + qkbase + (size_t)(qt * 64 + sr) * EMB + sc;
        *(uint4*)&Qs[sr * LDP + sc]     = *(const uint4*)src;
        *(uint4*)&Qs[sr * LDP + sc + 8] = *(const uint4*)(src + 8);
    }
    __syncthreads();
    short8 aq0 = *(const short8*)&Qs[(wrow + l15) * LDP + quad * 8];
    short8 aq1 = *(const short8*)&Qs[(wrow + l15) * LDP + 32 + quad * 8];

    f32x4 acc_o[4];
#pragma unroll
    for (int nd = 0; nd < 4; ++nd) acc_o[nd] = (f32x4){0.f, 0.f, 0.f, 0.f};
    float m_i[4] = {-3.0e38f, -3.0e38f, -3.0e38f, -3.0e38f};
    float l_i[4] = {0.f, 0.f, 0.f, 0.f};
    const float scale = 0.03125f;     // 1024^-0.5
    const int   rowg0 = qt * 64 + wrow + quad * 4;

    for (int kt = 0; kt <= qt; ++kt) {
        __syncthreads();
        {
            const ushort* ksrc = Kb + qkbase + (size_t)(kt * 64 + sr) * EMB + sc;
            *(uint4*)&Ks[sr * LDP + sc]     = *(const uint4*)ksrc;
            *(uint4*)&Ks[sr * LDP + sc + 8] = *(const uint4*)(ksrc + 8);
            const ushort* vsrc = Vt + ((size_t)bh * 64 + sr) * SEQ + kt * 64 + sc;
            *(uint4*)&Vs[sr * LDP + sc]     = *(const uint4*)vsrc;
            *(uint4*)&Vs[sr * LDP + sc + 8] = *(const uint4*)(vsrc + 8);
        }
        __syncthreads();

        // ---- S = Q K^T (wave: 16 rows x 64 keys) ----
        f32x4 sc4[4];
#pragma unroll
        for (int ni = 0; ni < 4; ++ni) {
            short8 bk0 = *(const short8*)&Ks[(ni * 16 + l15) * LDP + quad * 8];
            short8 bk1 = *(const short8*)&Ks[(ni * 16 + l15) * LDP + 32 + quad * 8];
            f32x4 a = (f32x4){0.f, 0.f, 0.f, 0.f};
            a = __builtin_amdgcn_mfma_f32_16x16x32_bf16(aq0, bk0, a, 0, 0, 0);
            a = __builtin_amdgcn_mfma_f32_16x16x32_bf16(aq1, bk1, a, 0, 0, 0);
            sc4[ni] = a;
        }

        // ---- online softmax ----
        const bool diag = (kt == qt);
        float sv[4][4], mnew[4];
#pragma unroll
        for (int r = 0; r < 4; ++r) mnew[r] = m_i[r];
#pragma unroll
        for (int ni = 0; ni < 4; ++ni) {
            int col = kt * 64 + ni * 16 + l15;
#pragma unroll
            for (int r = 0; r < 4; ++r) {
                float v = sc4[ni][r] * scale;
                if (diag && col > rowg0 + r) v = -3.0e38f;
                sv[ni][r] = v;
                mnew[r] = fmaxf(mnew[r], v);
            }
        }
#pragma unroll
        for (int r = 0; r < 4; ++r) {
            mnew[r] = fmaxf(mnew[r], __shfl_xor(mnew[r], 1, 64));
            mnew[r] = fmaxf(mnew[r], __shfl_xor(mnew[r], 2, 64));
            mnew[r] = fmaxf(mnew[r], __shfl_xor(mnew[r], 4, 64));
            mnew[r] = fmaxf(mnew[r], __shfl_xor(mnew[r], 8, 64));
        }
        float alpha[4], rsum[4];
#pragma unroll
        for (int r = 0; r < 4; ++r) {
            alpha[r] = __expf(m_i[r] - mnew[r]);
            m_i[r] = mnew[r];
        }
        float p[4][4];
#pragma unroll
        for (int ni = 0; ni < 4; ++ni)
#pragma unroll
            for (int r = 0; r < 4; ++r)
                p[ni][r] = __expf(sv[ni][r] - mnew[r]);
#pragma unroll
        for (int r = 0; r < 4; ++r) {
            rsum[r] = p[0][r] + p[1][r] + p[2][r] + p[3][r];
            rsum[r] += __shfl_xor(rsum[r], 1, 64);
            rsum[r] += __shfl_xor(rsum[r], 2, 64);
            rsum[r] += __shfl_xor(rsum[r], 4, 64);
            rsum[r] += __shfl_xor(rsum[r], 8, 64);
            l_i[r] = l_i[r] * alpha[r] + rsum[r];
        }
#pragma unroll
        for (int nd = 0; nd < 4; ++nd)
#pragma unroll
            for (int r = 0; r < 4; ++r)
                acc_o[nd][r] *= alpha[r];

        // ---- P: C-layout -> A-layout via per-wave LDS region ----
        ushort* Pw = &Ps[wrow * LDP];
#pragma unroll
        for (int ni = 0; ni < 4; ++ni)
#pragma unroll
            for (int r = 0; r < 4; ++r)
                Pw[(quad * 4 + r) * LDP + ni * 16 + l15] = bf16_1(p[ni][r]);
        __syncthreads();

        short8 pa0 = *(const short8*)&Ps[(wrow + l15) * LDP + quad * 8];
        short8 pa1 = *(const short8*)&Ps[(wrow + l15) * LDP + 32 + quad * 8];
#pragma unroll
        for (int nd = 0; nd < 4; ++nd) {
            short8 bv0 = *(const short8*)&Vs[(nd * 16 + l15) * LDP + quad * 8];
            short8 bv1 = *(const short8*)&Vs[(nd * 16 + l15) * LDP + 32 + quad * 8];
            acc_o[nd] = __builtin_amdgcn_mfma_f32_16x16x32_bf16(pa0, bv0, acc_o[nd], 0, 0, 0);
            acc_o[nd] = __builtin_amdgcn_mfma_f32_16x16x32_bf16(pa1, bv1, acc_o[nd], 0, 0, 0);
        }
    }

    // ---- epilogue ----
    float inv[4];
#pragma unroll
    for (int r = 0; r < 4; ++r) inv[r] = 1.0f / l_i[r];
#pragma unroll
    for (int nd = 0; nd < 4; ++nd)
#pragma unroll
        for (int r = 0; r < 4; ++r) {
            int row = qt * 64 + wrow + quad * 4 + r;
            AOb[(size_t)(b * SEQ + row) * EMB + h * 64 + nd * 16 + l15] =
                bf16_1(acc_o[nd][r] * inv[r]);
        }
}

// ---------------- fp32 fallback GEMM ----------------
#define BM 64
#define BN 64
#define BK 16

__global__ __launch_bounds__(256) void gemm_f32(
    const float* __restrict__ A, const float* __restrict__ B,
    float* __restrict__ C, const float* __restrict__ pos, int addpos,
    int M, int N, int K) {
    __shared__ float As[BK][BM];
    __shared__ float Bs[BK][BN];
    const int tid = threadIdx.x;
    const int bm  = blockIdx.x * BM;
    const int bn  = blockIdx.y * BN;
    const int tx  = tid & 15;
    const int ty  = tid >> 4;
    const int arow = tid >> 2;
    const int acol = (tid & 3) << 2;
    const int brow = tid >> 4;
    const int bcol = (tid & 15) << 2;
    float acc[4][4] = {{0.f}};
    const float* Aptr = A + (size_t)(bm + arow) * K + acol;
    const float* Bptr = B + (size_t)brow * N + bn + bcol;
    for (int k0 = 0; k0 < K; k0 += BK) {
        float4 av = *(const float4*)(Aptr + k0);
        float4 bv = *(const float4*)(Bptr + (size_t)k0 * N);
        __syncthreads();
        As[acol + 0][arow] = av.x;
        As[acol + 1][arow] = av.y;
        As[acol + 2][arow] = av.z;
        As[acol + 3][arow] = av.w;
        *(float4*)&Bs[brow][bcol] = bv;
        __syncthreads();
#pragma unroll
        for (int kk = 0; kk < BK; ++kk) {
            float4 a = *(const float4*)&As[kk][ty << 2];
            float4 b = *(const float4*)&Bs[kk][tx << 2];
            float aa[4] = {a.x, a.y, a.z, a.w};
            float bb[4] = {b.x, b.y, b.z, b.w};
#pragma unroll
            for (int i = 0; i < 4; ++i)
#pragma unroll
                for (int j = 0; j < 4; ++j)
                    acc[i][j] += aa[i] * bb[j];
        }
    }
#pragma unroll
    for (int i = 0; i < 4; ++i) {
        int m = bm + (ty << 2) + i;
        int n = bn + (tx << 2);
        float4 v = make_float4(acc[i][0], acc[i][1], acc[i][2], acc[i][3]);
        if (addpos) {
            int s = m & (SEQ - 1);
            int d = n & (DHEAD - 1);
            float4 p = *(const float4*)&pos[s * DHEAD + d];
            v.x += p.x; v.y += p.y; v.z += p.z; v.w += p.w;
        }
        *(float4*)&C[(size_t)m * N + n] = v;
    }
}

// ---------------- fp32 fallback attention ----------------
#define QT 128
#define KT 32
__global__ __launch_bounds__(QT) void attn_fwd(
    const float* __restrict__ Q, const float* __restrict__ Kg,
    const float* __restrict__ V, float* __restrict__ O) {
    __shared__ float Ks[KT][DHEAD];
    __shared__ float Vs[KT][DHEAD];
    const int t    = threadIdx.x;
    const int q0   = blockIdx.x * QT;
    const int bh   = blockIdx.y;
    const int b    = bh >> 4;
    const int h    = bh & 15;
    const int qrow = q0 + t;
    const size_t base = (size_t)b * SEQ * EMB + (size_t)h * DHEAD;
    float4 q4[16], o4[16];
#pragma unroll
    for (int i = 0; i < 16; ++i) {
        q4[i] = *(const float4*)&Q[base + (size_t)qrow * EMB + i * 4];
        o4[i] = make_float4(0.f, 0.f, 0.f, 0.f);
    }
    float m_i = -3.0e38f, l_i = 0.0f;
    const float scale = 0.03125f;
    const int kend = q0 + QT;
    for (int k0 = 0; k0 < kend; k0 += KT) {
        __syncthreads();
#pragma unroll
        for (int i = 0; i < 4; ++i) {
            int idx = t + i * QT;
            int r = idx >> 4;
            int c = (idx & 15) << 2;
            *(float4*)&Ks[r][c] = *(const float4*)&Kg[base + (size_t)(k0 + r) * EMB + c];
            *(float4*)&Vs[r][c] = *(const float4*)&V [base + (size_t)(k0 + r) * EMB + c];
        }
        __syncthreads();
        float sv[KT];
        float mt = m_i;
#pragma unroll
        for (int j = 0; j < KT; ++j) {
            const float4* kr = (const float4*)Ks[j];
            float dot = 0.f;
#pragma unroll
            for (int dd = 0; dd < 16; ++dd) {
                float4 kv = kr[dd];
                dot += q4[dd].x * kv.x + q4[dd].y * kv.y +
                       q4[dd].z * kv.z + q4[dd].w * kv.w;
            }
            sv[j] = (k0 + j <= qrow) ? dot * scale : -3.0e38f;
            mt = fmaxf(mt, sv[j]);
        }
        float corr = __expf(m_i - mt);
        l_i *= corr;
#pragma unroll
        for (int i = 0; i < 16; ++i) {
            o4[i].x *= corr; o4[i].y *= corr; o4[i].z *= corr; o4[i].w *= corr;
        }
#pragma unroll
        for (int j = 0; j < KT; ++j) {
            float pp = __expf(sv[j] - mt);
            l_i += pp;
            const float4* vr = (const float4*)Vs[j];
#pragma unroll
            for (int dd = 0; dd < 16; ++dd) {
                float4 vv = vr[dd];
                o4[dd].x += pp * vv.x; o4[dd].y += pp * vv.y;
                o4[dd].z += pp * vv.z; o4[dd].w += pp * vv.w;
            }
        }
        m_i = mt;
    }
    float inv = 1.0f / l_i;
#pragma unroll
    for (int i = 0; i < 16; ++i) {
        float4 v = o4[i];
        v.x *= inv; v.y *= inv; v.z *= inv; v.w *= inv;
        *(float4*)&O[base + (size_t)qrow * EMB + i * 4] = v;
    }
}

// ---------------- launch ----------------
extern "C" void kernel_launch(void* const* d_in, const int* in_sizes, int n_in,
                              void* d_out, int out_size, void* d_ws, size_t ws_size,
                              hipStream_t stream) {
    const float* x  = (const float*)d_in[0];
    const float* Wq = (const float*)d_in[1];
    const float* Wk = (const float*)d_in[2];
    const float* Wv = (const float*)d_in[3];
    const float* Wo = (const float*)d_in[4];
    float* out = (float*)d_out;

    char* ws = (char*)d_ws;

    // bf16 pipeline layout
    size_t off = 0;
    float*  pos  = (float*)(ws + off);  off += (size_t)SEQ * DHEAD * 4;
    ushort* xb   = (ushort*)(ws + off); off += (size_t)MROWS * EMB * 2;
    ushort* Wqt  = (ushort*)(ws + off); off += (size_t)EMB * EMB * 2;
    ushort* Wkt  = (ushort*)(ws + off); off += (size_t)EMB * EMB * 2;
    ushort* Wvt  = (ushort*)(ws + off); off += (size_t)EMB * EMB * 2;
    ushort* Wot  = (ushort*)(ws + off); off += (size_t)EMB * EMB * 2;
    ushort* Qb16 = (ushort*)(ws + off); off += (size_t)MROWS * EMB * 2;
    ushort* Kb16 = (ushort*)(ws + off); off += (size_t)MROWS * EMB * 2;
    ushort* Vb16 = (ushort*)(ws + off); off += (size_t)MROWS * EMB * 2;
    ushort* Vtp  = (ushort*)(ws + off); off += (size_t)MROWS * EMB * 2;
    ushort* AOb  = (ushort*)(ws + off); off += (size_t)MROWS * EMB * 2;
    const bool use_bf16 = off <= ws_size;

    const int M = MROWS, N = EMB, K = EMB;

    pos_init<<<SEQ, DHEAD, 0, stream>>>(pos);

    if (use_bf16) {
        const int n2 = MROWS * EMB / 2;
        cvt_bf16<<<n2 / 256, 256, 0, stream>>>(x, xb, n2);
        dim3 wtg(EMB / 32, EMB / 32);
        wt_bf16<<<wtg, 256, 0, stream>>>(Wq, Wqt);
        wt_bf16<<<wtg, 256, 0, stream>>>(Wk, Wkt);
        wt_bf16<<<wtg, 256, 0, stream>>>(Wv, Wvt);
        wt_bf16<<<wtg, 256, 0, stream>>>(Wo, Wot);

        dim3 gg(M / GBM, N / GBN);
        gemm_mfma<<<gg, 256, 0, stream>>>(xb, Wqt, Qb16, pos, 1, 1, N, K);
        gemm_mfma<<<gg, 256, 0, stream>>>(xb, Wkt, Kb16, pos, 1, 1, N, K);
        gemm_mfma<<<gg, 256, 0, stream>>>(xb, Wvt, Vb16, pos, 0, 1, N, K);

        vt_tr<<<dim3(SEQ / 64, BATCH * NHEAD), 256, 0, stream>>>(Vb16, Vtp);

        attn_mfma<<<dim3(SEQ / 64, BATCH * NHEAD), 256, 0, stream>>>(
            Qb16, Kb16, Vtp, AOb);

        gemm_mfma<<<gg, 256, 0, stream>>>(AOb, Wot, out, pos, 0, 0, N, K);
    } else {
        // fp32 fallback
        size_t f = 0;
        float* posf = (float*)(ws + f); f += (size_t)SEQ * DHEAD * 4;
        float* Qb = (float*)(ws + f); f += (size_t)MROWS * EMB * 4;
        float* Kb = (float*)(ws + f); f += (size_t)MROWS * EMB * 4;
        float* Vb = (float*)(ws + f); f += (size_t)MROWS * EMB * 4;
        float* AO = (float*)(ws + f);
        dim3 g(M / BM, N / BN);
        gemm_f32<<<g, 256, 0, stream>>>(x, Wq, Qb, posf, 1, M, N, K);
        gemm_f32<<<g, 256, 0, stream>>>(x, Wk, Kb, posf, 1, M, N, K);
        gemm_f32<<<g, 256, 0, stream>>>(x, Wv, Vb, posf, 0, M, N, K);
        attn_fwd<<<dim3(SEQ / QT, BATCH * NHEAD), QT, 0, stream>>>(Qb, Kb, Vb, AO);
        gemm_f32<<<g, 256, 0, stream>>>(AO, Wo, out, posf, 0, M, N, K);
    }
}

// Round 5
// 242.537 us; speedup vs baseline: 24.3483x; 1.1977x over previous
//
#include <hip/hip_runtime.h>
#include <math.h>

#define BATCH 2
#define SEQ   2048
#define EMB   1024
#define NHEAD 16
#define DHEAD 64
#define MROWS (BATCH*SEQ)
#define QKVS  3072          // fused QKV row stride

typedef unsigned int  uint;
typedef unsigned short ushort;
typedef __attribute__((ext_vector_type(8))) short short8;
typedef __attribute__((ext_vector_type(4))) float f32x4;

// ---------------- positional encoding table ----------------
__global__ void pos_init(float* __restrict__ pos) {
    int s = blockIdx.x;
    int d = threadIdx.x;              // 0..63
    int i = d >> 1;
    float expo  = (float)(2 * i) / (float)DHEAD;
    float scale = 1.0f / (powf(10000.0f, expo) + 1.1920928955078125e-07f);
    float ang   = (float)s * scale;
    pos[s * DHEAD + d] = (d & 1) ? cosf(ang) : sinf(ang);
}

// ---------------- bf16 helpers ----------------
__device__ __forceinline__ uint pack_bf16x2(float a, float b) {
    union { float f; uint u; } x, y;
    x.f = a; y.f = b;
    uint ua = x.u + 0x7fffu + ((x.u >> 16) & 1u);   // RNE
    uint ub = y.u + 0x7fffu + ((y.u >> 16) & 1u);
    return (ua >> 16) | (ub & 0xffff0000u);
}
__device__ __forceinline__ ushort bf16_1(float a) {
    union { float f; uint u; } x; x.f = a;
    return (ushort)((x.u + 0x7fffu + ((x.u >> 16) & 1u)) >> 16);
}

// async global->LDS, 16B per lane (lds dest = wave-uniform base + lane*16)
__device__ __forceinline__ void gll16(const ushort* g, ushort* l) {
    __builtin_amdgcn_global_load_lds(
        (const __attribute__((address_space(1))) uint*)g,
        (__attribute__((address_space(3))) uint*)l, 16, 0, 0);
}

// ---------------- fp32 -> bf16 (rowmajor) ----------------
__global__ __launch_bounds__(256) void cvt_bf16(
    const float* __restrict__ in, ushort* __restrict__ out, int n2) {
    int gid = blockIdx.x * 256 + threadIdx.x;
    if (gid < n2) {
        float2 v = ((const float2*)in)[gid];
        ((uint*)out)[gid] = pack_bf16x2(v.x, v.y);
    }
}

// ---------------- W[K][N] fp32 -> Wt[N][K] bf16 (transpose) ----------------
__global__ __launch_bounds__(256) void wt_bf16(
    const float* __restrict__ W, ushort* __restrict__ Wt) {
    __shared__ float tile[32][33];
    const int c0 = blockIdx.x * 32;   // n-tile
    const int r0 = blockIdx.y * 32;   // k-tile
    const int tx = threadIdx.x & 31;
    const int ty = threadIdx.x >> 5;  // 0..7
#pragma unroll
    for (int i = 0; i < 4; ++i)
        tile[ty + i * 8][tx] = W[(size_t)(r0 + ty + i * 8) * EMB + c0 + tx];
    __syncthreads();
#pragma unroll
    for (int i = 0; i < 4; ++i)
        Wt[(size_t)(c0 + ty + i * 8) * EMB + r0 + tx] = bf16_1(tile[tx][ty + i * 8]);
}

// ---- QKV bf16 [token][3072] (V at col 2048) -> Vt bf16 [bh][64][SEQ] ------
__global__ __launch_bounds__(256) void vt_tr(
    const ushort* __restrict__ QKV, ushort* __restrict__ Vt) {
    __shared__ ushort tile[64][72];
    const int s0 = blockIdx.x * 64;
    const int bh = blockIdx.y;
    const int b  = bh >> 4, h = bh & 15;
    const int t  = threadIdx.x;
    const int r  = t >> 2;             // 0..63
    const int c  = (t & 3) * 16;       // 0,16,32,48
    const ushort* src = QKV + (size_t)(b * SEQ + s0 + r) * QKVS + 2048 + h * 64 + c;
    *(uint4*)&tile[r][c]     = *(const uint4*)src;
    *(uint4*)&tile[r][c + 8] = *(const uint4*)(src + 8);
    __syncthreads();
    uint ov[8];
#pragma unroll
    for (int i = 0; i < 8; ++i) {
        uint lo = tile[c + 2 * i][r];
        uint hi = tile[c + 2 * i + 1][r];
        ov[i] = lo | (hi << 16);
    }
    ushort* dst = Vt + ((size_t)bh * 64 + r) * SEQ + s0 + c;
    *(uint4*)dst       = *(uint4*)&ov[0];
    *(uint4*)(dst + 8) = *(uint4*)&ov[4];
}

// ------- bf16 MFMA GEMM (m97 recipe): C[M,N] = A[M,K] @ Bt[N,K]^T ----------
// 128x128 tile, BK=32, 256 thr = 4 waves (2x2, each 64x64), global_load_lds.
#define TM 128
#define TN 128
#define TK 32

__global__ __launch_bounds__(256) void gemm_mfma2(
    const ushort* __restrict__ A, const ushort* __restrict__ Bt,
    void* __restrict__ Cv, const float* __restrict__ pos, int posmode,
    int out_bf16, int N, int K) {
    __shared__ ushort As[TM * TK];   // [m][k] contiguous (lane-linear for gll)
    __shared__ ushort Bs[TN * TK];   // [n][k]

    const int t    = threadIdx.x;
    const int lane = t & 63, w = t >> 6;
    const int quad = lane >> 4, l15 = lane & 15;
    const int bm = blockIdx.x * TM, bn = blockIdx.y * TN;
    const int wm = (w & 1) * 64, wn = (w >> 1) * 64;
    const int r0 = t >> 2, kp = (t & 3) * 8;   // staging row / k-part

    f32x4 acc[4][4];
#pragma unroll
    for (int mi = 0; mi < 4; ++mi)
#pragma unroll
        for (int ni = 0; ni < 4; ++ni)
            acc[mi][ni] = (f32x4){0.f, 0.f, 0.f, 0.f};

    const ushort* Ap0 = A  + (size_t)(bm + r0) * K + kp;
    const ushort* Ap1 = A  + (size_t)(bm + 64 + r0) * K + kp;
    const ushort* Bp0 = Bt + (size_t)(bn + r0) * K + kp;
    const ushort* Bp1 = Bt + (size_t)(bn + 64 + r0) * K + kp;
    ushort* Asd0 = &As[t * 8];            // == (r0*TK + kp)
    ushort* Asd1 = &As[2048 + t * 8];
    ushort* Bsd0 = &Bs[t * 8];
    ushort* Bsd1 = &Bs[2048 + t * 8];

    for (int k0 = 0; k0 < K; k0 += TK) {
        __syncthreads();
        gll16(Ap0 + k0, Asd0);
        gll16(Ap1 + k0, Asd1);
        gll16(Bp0 + k0, Bsd0);
        gll16(Bp1 + k0, Bsd1);
        __syncthreads();                   // drains vmcnt -> LDS valid

        short8 af[4], bfv[4];
#pragma unroll
        for (int mi = 0; mi < 4; ++mi)
            af[mi] = *(const short8*)&As[(wm + mi * 16 + l15) * TK + quad * 8];
#pragma unroll
        for (int ni = 0; ni < 4; ++ni)
            bfv[ni] = *(const short8*)&Bs[(wn + ni * 16 + l15) * TK + quad * 8];
#pragma unroll
        for (int mi = 0; mi < 4; ++mi)
#pragma unroll
            for (int ni = 0; ni < 4; ++ni)
                acc[mi][ni] = __builtin_amdgcn_mfma_f32_16x16x32_bf16(
                    af[mi], bfv[ni], acc[mi][ni], 0, 0, 0);
    }

#pragma unroll
    for (int mi = 0; mi < 4; ++mi) {
#pragma unroll
        for (int r = 0; r < 4; ++r) {
            const int row = bm + wm + mi * 16 + quad * 4 + r;
            const int s   = row & (SEQ - 1);
#pragma unroll
            for (int ni = 0; ni < 4; ++ni) {
                const int col = bn + wn + ni * 16 + l15;
                float v = acc[mi][ni][r];
                if (posmode && col < 2048) v += pos[s * DHEAD + (col & 63)];
                if (out_bf16) ((ushort*)Cv)[(size_t)row * N + col] = bf16_1(v);
                else          ((float*) Cv)[(size_t)row * N + col] = v;
            }
        }
    }
}

// -------- MFMA flash attention, S^T formulation + paired causal tiles ------
// block: q-tiles (pair, 31-pair) x one (b,h); 4 waves; wave owns 16 q-rows.
#define LDP 72   // padded LDS row stride in ushorts

__global__ __launch_bounds__(256) void attn_mfma2(
    const ushort* __restrict__ QKV, const ushort* __restrict__ Vt,
    ushort* __restrict__ AOb) {
    __shared__ ushort Qs[64 * LDP];
    __shared__ ushort Ks[64 * LDP];
    __shared__ ushort Vs[64 * LDP];
    __shared__ ushort Ps[64 * LDP];

    const int pair = blockIdx.x;          // 0..15
    const int bh   = blockIdx.y;
    const int b    = bh >> 4, h = bh & 15;
    const int t    = threadIdx.x;
    const int lane = t & 63, w = t >> 6;
    const int quad = lane >> 4, l15 = lane & 15;
    const int wrow = w * 16;
    const int sr = t >> 2;                // staging row 0..63
    const int sc = (t & 3) * 16;          // 0,16,32,48
    const float scale = 0.03125f;         // 1024^-0.5

    const size_t qbase = (size_t)b * SEQ * QKVS + h * 64;   // + row*QKVS

#pragma unroll
    for (int ph = 0; ph < 2; ++ph) {
        const int qt = ph ? (31 - pair) : pair;

        __syncthreads();
        {   // stage Q tile (64 x 64)
            const ushort* src = QKV + qbase + (size_t)(qt * 64 + sr) * QKVS + sc;
            *(uint4*)&Qs[sr * LDP + sc]     = *(const uint4*)src;
            *(uint4*)&Qs[sr * LDP + sc + 8] = *(const uint4*)(src + 8);
        }
        __syncthreads();
        const short8 aq0 = *(const short8*)&Qs[(wrow + l15) * LDP + quad * 8];
        const short8 aq1 = *(const short8*)&Qs[(wrow + l15) * LDP + 32 + quad * 8];

        f32x4 acc_o[4];
#pragma unroll
        for (int nd = 0; nd < 4; ++nd) acc_o[nd] = (f32x4){0.f, 0.f, 0.f, 0.f};
        float m_l = -3.0e38f, l_l = 0.f;          // softmax state for q = l15
        const int qrow_g = qt * 64 + wrow + l15;

        for (int kt = 0; kt <= qt; ++kt) {
            __syncthreads();
            {   // stage K tile and V^T tile
                const ushort* ksrc = QKV + qbase + 1024 + (size_t)(kt * 64 + sr) * QKVS + sc;
                *(uint4*)&Ks[sr * LDP + sc]     = *(const uint4*)ksrc;
                *(uint4*)&Ks[sr * LDP + sc + 8] = *(const uint4*)(ksrc + 8);
                const ushort* vsrc = Vt + ((size_t)bh * 64 + sr) * SEQ + kt * 64 + sc;
                *(uint4*)&Vs[sr * LDP + sc]     = *(const uint4*)vsrc;
                *(uint4*)&Vs[sr * LDP + sc + 8] = *(const uint4*)(vsrc + 8);
            }
            __syncthreads();

            // ---- S^T = K Q^T : lane holds (key=kg*16+quad*4+r, q=l15) ----
            float sv[4][4];
            float mloc = m_l;
            const bool diag = (kt == qt);
#pragma unroll
            for (int kg = 0; kg < 4; ++kg) {
                const short8 ak0 = *(const short8*)&Ks[(kg * 16 + l15) * LDP + quad * 8];
                const short8 ak1 = *(const short8*)&Ks[(kg * 16 + l15) * LDP + 32 + quad * 8];
                f32x4 a = (f32x4){0.f, 0.f, 0.f, 0.f};
                a = __builtin_amdgcn_mfma_f32_16x16x32_bf16(ak0, aq0, a, 0, 0, 0);
                a = __builtin_amdgcn_mfma_f32_16x16x32_bf16(ak1, aq1, a, 0, 0, 0);
                const int keyb = kt * 64 + kg * 16 + quad * 4;
#pragma unroll
                for (int r = 0; r < 4; ++r) {
                    float v = a[r] * scale;
                    if (diag && (keyb + r > qrow_g)) v = -3.0e38f;
                    sv[kg][r] = v;
                    mloc = fmaxf(mloc, v);
                }
            }
            mloc = fmaxf(mloc, __shfl_xor(mloc, 16, 64));
            mloc = fmaxf(mloc, __shfl_xor(mloc, 32, 64));
            const float alpha = __expf(m_l - mloc);
            m_l = mloc;
            float rs = 0.f;
#pragma unroll
            for (int kg = 0; kg < 4; ++kg)
#pragma unroll
                for (int r = 0; r < 4; ++r) {
                    float p = __expf(sv[kg][r] - mloc);
                    sv[kg][r] = p;
                    rs += p;
                }
            rs += __shfl_xor(rs, 16, 64);
            rs += __shfl_xor(rs, 32, 64);
            l_l = l_l * alpha + rs;

            // broadcast alpha to accumulator layout (row q = quad*4+r)
            float av[4];
#pragma unroll
            for (int r = 0; r < 4; ++r) av[r] = __shfl(alpha, quad * 4 + r, 64);
#pragma unroll
            for (int nd = 0; nd < 4; ++nd)
#pragma unroll
                for (int r = 0; r < 4; ++r) acc_o[nd][r] *= av[r];

            // ---- P[q][key] write: 4 x b64 per lane, conflict-free ----
#pragma unroll
            for (int kg = 0; kg < 4; ++kg) {
                uint2 u;
                u.x = pack_bf16x2(sv[kg][0], sv[kg][1]);
                u.y = pack_bf16x2(sv[kg][2], sv[kg][3]);
                *(uint2*)&Ps[(wrow + l15) * LDP + kg * 16 + quad * 4] = u;
            }
            // per-wave region: same-wave RAW, no barrier needed
            const short8 pa0 = *(const short8*)&Ps[(wrow + l15) * LDP + quad * 8];
            const short8 pa1 = *(const short8*)&Ps[(wrow + l15) * LDP + 32 + quad * 8];
#pragma unroll
            for (int nd = 0; nd < 4; ++nd) {
                const short8 bv0 = *(const short8*)&Vs[(nd * 16 + l15) * LDP + quad * 8];
                const short8 bv1 = *(const short8*)&Vs[(nd * 16 + l15) * LDP + 32 + quad * 8];
                acc_o[nd] = __builtin_amdgcn_mfma_f32_16x16x32_bf16(pa0, bv0, acc_o[nd], 0, 0, 0);
                acc_o[nd] = __builtin_amdgcn_mfma_f32_16x16x32_bf16(pa1, bv1, acc_o[nd], 0, 0, 0);
            }
        }

        // ---- epilogue: fetch l for q=quad*4+r, normalize, store bf16 ----
        float linv[4];
#pragma unroll
        for (int r = 0; r < 4; ++r) linv[r] = 1.0f / __shfl(l_l, quad * 4 + r, 64);
#pragma unroll
        for (int nd = 0; nd < 4; ++nd)
#pragma unroll
            for (int r = 0; r < 4; ++r) {
                const int row = qt * 64 + wrow + quad * 4 + r;
                AOb[(size_t)(b * SEQ + row) * EMB + h * 64 + nd * 16 + l15] =
                    bf16_1(acc_o[nd][r] * linv[r]);
            }
    }
}

// ---------------- fp32 fallback GEMM ----------------
#define BM 64
#define BN 64
#define BK 16

__global__ __launch_bounds__(256) void gemm_f32(
    const float* __restrict__ A, const float* __restrict__ B,
    float* __restrict__ C, const float* __restrict__ pos, int addpos,
    int M, int N, int K) {
    __shared__ float As[BK][BM];
    __shared__ float Bs[BK][BN];
    const int tid = threadIdx.x;
    const int bm  = blockIdx.x * BM;
    const int bn  = blockIdx.y * BN;
    const int tx  = tid & 15;
    const int ty  = tid >> 4;
    const int arow = tid >> 2;
    const int acol = (tid & 3) << 2;
    const int brow = tid >> 4;
    const int bcol = (tid & 15) << 2;
    float acc[4][4] = {{0.f}};
    const float* Aptr = A + (size_t)(bm + arow) * K + acol;
    const float* Bptr = B + (size_t)brow * N + bn + bcol;
    for (int k0 = 0; k0 < K; k0 += BK) {
        float4 av = *(const float4*)(Aptr + k0);
        float4 bv = *(const float4*)(Bptr + (size_t)k0 * N);
        __syncthreads();
        As[acol + 0][arow] = av.x;
        As[acol + 1][arow] = av.y;
        As[acol + 2][arow] = av.z;
        As[acol + 3][arow] = av.w;
        *(float4*)&Bs[brow][bcol] = bv;
        __syncthreads();
#pragma unroll
        for (int kk = 0; kk < BK; ++kk) {
            float4 a = *(const float4*)&As[kk][ty << 2];
            float4 b = *(const float4*)&Bs[kk][tx << 2];
            float aa[4] = {a.x, a.y, a.z, a.w};
            float bb[4] = {b.x, b.y, b.z, b.w};
#pragma unroll
            for (int i = 0; i < 4; ++i)
#pragma unroll
                for (int j = 0; j < 4; ++j)
                    acc[i][j] += aa[i] * bb[j];
        }
    }
#pragma unroll
    for (int i = 0; i < 4; ++i) {
        int m = bm + (ty << 2) + i;
        int n = bn + (tx << 2);
        float4 v = make_float4(acc[i][0], acc[i][1], acc[i][2], acc[i][3]);
        if (addpos) {
            int s = m & (SEQ - 1);
            int d = n & (DHEAD - 1);
            float4 p = *(const float4*)&pos[s * DHEAD + d];
            v.x += p.x; v.y += p.y; v.z += p.z; v.w += p.w;
        }
        *(float4*)&C[(size_t)m * N + n] = v;
    }
}

// ---------------- fp32 fallback attention ----------------
#define QT 128
#define KT 32
__global__ __launch_bounds__(QT) void attn_fwd(
    const float* __restrict__ Q, const float* __restrict__ Kg,
    const float* __restrict__ V, float* __restrict__ O) {
    __shared__ float Ks[KT][DHEAD];
    __shared__ float Vs[KT][DHEAD];
    const int t    = threadIdx.x;
    const int q0   = blockIdx.x * QT;
    const int bh   = blockIdx.y;
    const int b    = bh >> 4;
    const int h    = bh & 15;
    const int qrow = q0 + t;
    const size_t base = (size_t)b * SEQ * EMB + (size_t)h * DHEAD;
    float4 q4[16], o4[16];
#pragma unroll
    for (int i = 0; i < 16; ++i) {
        q4[i] = *(const float4*)&Q[base + (size_t)qrow * EMB + i * 4];
        o4[i] = make_float4(0.f, 0.f, 0.f, 0.f);
    }
    float m_i = -3.0e38f, l_i = 0.0f;
    const float scale = 0.03125f;
    const int kend = q0 + QT;
    for (int k0 = 0; k0 < kend; k0 += KT) {
        __syncthreads();
#pragma unroll
        for (int i = 0; i < 4; ++i) {
            int idx = t + i * QT;
            int r = idx >> 4;
            int c = (idx & 15) << 2;
            *(float4*)&Ks[r][c] = *(const float4*)&Kg[base + (size_t)(k0 + r) * EMB + c];
            *(float4*)&Vs[r][c] = *(const float4*)&V [base + (size_t)(k0 + r) * EMB + c];
        }
        __syncthreads();
        float sv[KT];
        float mt = m_i;
#pragma unroll
        for (int j = 0; j < KT; ++j) {
            const float4* kr = (const float4*)Ks[j];
            float dot = 0.f;
#pragma unroll
            for (int dd = 0; dd < 16; ++dd) {
                float4 kv = kr[dd];
                dot += q4[dd].x * kv.x + q4[dd].y * kv.y +
                       q4[dd].z * kv.z + q4[dd].w * kv.w;
            }
            sv[j] = (k0 + j <= qrow) ? dot * scale : -3.0e38f;
            mt = fmaxf(mt, sv[j]);
        }
        float corr = __expf(m_i - mt);
        l_i *= corr;
#pragma unroll
        for (int i = 0; i < 16; ++i) {
            o4[i].x *= corr; o4[i].y *= corr; o4[i].z *= corr; o4[i].w *= corr;
        }
#pragma unroll
        for (int j = 0; j < KT; ++j) {
            float pp = __expf(sv[j] - mt);
            l_i += pp;
            const float4* vr = (const float4*)Vs[j];
#pragma unroll
            for (int dd = 0; dd < 16; ++dd) {
                float4 vv = vr[dd];
                o4[dd].x += pp * vv.x; o4[dd].y += pp * vv.y;
                o4[dd].z += pp * vv.z; o4[dd].w += pp * vv.w;
            }
        }
        m_i = mt;
    }
    float inv = 1.0f / l_i;
#pragma unroll
    for (int i = 0; i < 16; ++i) {
        float4 v = o4[i];
        v.x *= inv; v.y *= inv; v.z *= inv; v.w *= inv;
        *(float4*)&O[base + (size_t)qrow * EMB + i * 4] = v;
    }
}

// ---------------- launch ----------------
extern "C" void kernel_launch(void* const* d_in, const int* in_sizes, int n_in,
                              void* d_out, int out_size, void* d_ws, size_t ws_size,
                              hipStream_t stream) {
    const float* x  = (const float*)d_in[0];
    const float* Wq = (const float*)d_in[1];
    const float* Wk = (const float*)d_in[2];
    const float* Wv = (const float*)d_in[3];
    const float* Wo = (const float*)d_in[4];
    float* out = (float*)d_out;

    char* ws = (char*)d_ws;
    size_t off = 0;
    float*  pos   = (float*)(ws + off);  off += (size_t)SEQ * DHEAD * 4;
    ushort* xb    = (ushort*)(ws + off); off += (size_t)MROWS * EMB * 2;
    ushort* Wqkvt = (ushort*)(ws + off); off += (size_t)QKVS * EMB * 2;
    ushort* Wot   = (ushort*)(ws + off); off += (size_t)EMB * EMB * 2;
    ushort* QKV   = (ushort*)(ws + off); off += (size_t)MROWS * QKVS * 2;
    ushort* Vtp   = (ushort*)(ws + off); off += (size_t)MROWS * EMB * 2;
    ushort* AOb   = (ushort*)(ws + off); off += (size_t)MROWS * EMB * 2;
    const bool use_bf16 = off <= ws_size;

    const int M = MROWS, K = EMB;

    pos_init<<<SEQ, DHEAD, 0, stream>>>(pos);

    if (use_bf16) {
        const int n2 = MROWS * EMB / 2;
        cvt_bf16<<<n2 / 256, 256, 0, stream>>>(x, xb, n2);
        dim3 wtg(EMB / 32, EMB / 32);
        wt_bf16<<<wtg, 256, 0, stream>>>(Wq, Wqkvt);
        wt_bf16<<<wtg, 256, 0, stream>>>(Wk, Wqkvt + (size_t)1024 * EMB);
        wt_bf16<<<wtg, 256, 0, stream>>>(Wv, Wqkvt + (size_t)2048 * EMB);
        wt_bf16<<<wtg, 256, 0, stream>>>(Wo, Wot);

        // fused QKV projection: [4096,1024] @ [1024,3072] -> bf16 + pos
        gemm_mfma2<<<dim3(M / TM, QKVS / TN), 256, 0, stream>>>(
            xb, Wqkvt, QKV, pos, 1, 1, QKVS, K);

        vt_tr<<<dim3(SEQ / 64, BATCH * NHEAD), 256, 0, stream>>>(QKV, Vtp);

        attn_mfma2<<<dim3(16, BATCH * NHEAD), 256, 0, stream>>>(QKV, Vtp, AOb);

        gemm_mfma2<<<dim3(M / TM, EMB / TN), 256, 0, stream>>>(
            AOb, Wot, out, pos, 0, 0, EMB, K);
    } else {
        // fp32 fallback
        size_t f = 0;
        float* posf = (float*)(ws + f); f += (size_t)SEQ * DHEAD * 4;
        float* Qb = (float*)(ws + f); f += (size_t)MROWS * EMB * 4;
        float* Kb = (float*)(ws + f); f += (size_t)MROWS * EMB * 4;
        float* Vb = (float*)(ws + f); f += (size_t)MROWS * EMB * 4;
        float* AO = (float*)(ws + f);
        dim3 g(M / BM, EMB / BN);
        gemm_f32<<<g, 256, 0, stream>>>(x, Wq, Qb, posf, 1, M, EMB, K);
        gemm_f32<<<g, 256, 0, stream>>>(x, Wk, Kb, posf, 1, M, EMB, K);
        gemm_f32<<<g, 256, 0, stream>>>(x, Wv, Vb, posf, 0, M, EMB, K);
        attn_fwd<<<dim3(SEQ / QT, BATCH * NHEAD), QT, 0, stream>>>(Qb, Kb, Vb, AO);
        gemm_f32<<<g, 256, 0, stream>>>(AO, Wo, out, posf, 0, M, EMB, K);
    }
}

// Round 7
// 218.518 us; speedup vs baseline: 27.0247x; 1.1099x over previous
//
#include <hip/hip_runtime.h>
#include <math.h>

#define BATCH 2
#define SEQ   2048
#define EMB   1024
#define NHEAD 16
#define DHEAD 64
#define MROWS (BATCH*SEQ)
#define QKVS  3072          // fused QKV row stride

typedef unsigned int  uint;
typedef unsigned short ushort;
typedef __attribute__((ext_vector_type(8))) short short8;
typedef __attribute__((ext_vector_type(4))) float f32x4;

// fast 2^x (bare v_exp_f32; avoids glibc __exp2f macro collision)
__device__ __forceinline__ float exp2_fast(float x) {
    return __builtin_amdgcn_exp2f(x);
}

// ---------------- positional encoding table ----------------
__global__ void pos_init(float* __restrict__ pos) {
    int s = blockIdx.x;
    int d = threadIdx.x;              // 0..63
    int i = d >> 1;
    float expo  = (float)(2 * i) / (float)DHEAD;
    float scale = 1.0f / (powf(10000.0f, expo) + 1.1920928955078125e-07f);
    float ang   = (float)s * scale;
    pos[s * DHEAD + d] = (d & 1) ? cosf(ang) : sinf(ang);
}

// ---------------- bf16 helpers ----------------
__device__ __forceinline__ uint pack_bf16x2(float a, float b) {
    union { float f; uint u; } x, y;
    x.f = a; y.f = b;
    uint ua = x.u + 0x7fffu + ((x.u >> 16) & 1u);   // RNE
    uint ub = y.u + 0x7fffu + ((y.u >> 16) & 1u);
    return (ua >> 16) | (ub & 0xffff0000u);
}
__device__ __forceinline__ ushort bf16_1(float a) {
    union { float f; uint u; } x; x.f = a;
    return (ushort)((x.u + 0x7fffu + ((x.u >> 16) & 1u)) >> 16);
}

// async global->LDS, 16B per lane (lds dest = wave-uniform base + lane*16)
__device__ __forceinline__ void gll16(const ushort* g, ushort* l) {
    __builtin_amdgcn_global_load_lds(
        (const __attribute__((address_space(1))) uint*)g,
        (__attribute__((address_space(3))) uint*)l, 16, 0, 0);
}

// ---------------- fp32 -> bf16 (rowmajor) ----------------
__global__ __launch_bounds__(256) void cvt_bf16(
    const float* __restrict__ in, ushort* __restrict__ out, int n2) {
    int gid = blockIdx.x * 256 + threadIdx.x;
    if (gid < n2) {
        float2 v = ((const float2*)in)[gid];
        ((uint*)out)[gid] = pack_bf16x2(v.x, v.y);
    }
}

// ------- all 4 weights: W[K][N] fp32 -> Wt[N][K] bf16 (transpose) ----------
__global__ __launch_bounds__(256) void wt_bf16_all(
    const float* __restrict__ Wq, const float* __restrict__ Wk,
    const float* __restrict__ Wv, const float* __restrict__ Wo,
    ushort* __restrict__ Wqkvt, ushort* __restrict__ Wot) {
    __shared__ float tile[32][33];
    const int which = blockIdx.z;
    const float* W = (which == 0) ? Wq : (which == 1) ? Wk : (which == 2) ? Wv : Wo;
    ushort* Wt = (which < 3) ? (Wqkvt + (size_t)which * 1024 * EMB) : Wot;
    const int c0 = blockIdx.x * 32;   // n-tile
    const int r0 = blockIdx.y * 32;   // k-tile
    const int tx = threadIdx.x & 31;
    const int ty = threadIdx.x >> 5;  // 0..7
#pragma unroll
    for (int i = 0; i < 4; ++i)
        tile[ty + i * 8][tx] = W[(size_t)(r0 + ty + i * 8) * EMB + c0 + tx];
    __syncthreads();
#pragma unroll
    for (int i = 0; i < 4; ++i)
        Wt[(size_t)(c0 + ty + i * 8) * EMB + r0 + tx] = bf16_1(tile[tx][ty + i * 8]);
}

// ---- QKV bf16 [token][3072] (V at col 2048) -> Vt bf16 [bh][64][SEQ] ------
__global__ __launch_bounds__(256) void vt_tr(
    const ushort* __restrict__ QKV, ushort* __restrict__ Vt) {
    __shared__ ushort tile[64][72];
    const int s0 = blockIdx.x * 64;
    const int bh = blockIdx.y;
    const int b  = bh >> 4, h = bh & 15;
    const int t  = threadIdx.x;
    const int r  = t >> 2;             // 0..63
    const int c  = (t & 3) * 16;       // 0,16,32,48
    const ushort* src = QKV + (size_t)(b * SEQ + s0 + r) * QKVS + 2048 + h * 64 + c;
    *(uint4*)&tile[r][c]     = *(const uint4*)src;
    *(uint4*)&tile[r][c + 8] = *(const uint4*)(src + 8);
    __syncthreads();
    uint ov[8];
#pragma unroll
    for (int i = 0; i < 8; ++i) {
        uint lo = tile[c + 2 * i][r];
        uint hi = tile[c + 2 * i + 1][r];
        ov[i] = lo | (hi << 16);
    }
    ushort* dst = Vt + ((size_t)bh * 64 + r) * SEQ + s0 + c;
    *(uint4*)dst       = *(uint4*)&ov[0];
    *(uint4*)(dst + 8) = *(uint4*)&ov[4];
}

// ------- bf16 MFMA GEMM (m97 recipe): C[M,N] = A[M,K] @ Bt[N,K]^T ----------
#define TM 128
#define TN 128
#define TK 32

__global__ __launch_bounds__(256) void gemm_mfma2(
    const ushort* __restrict__ A, const ushort* __restrict__ Bt,
    void* __restrict__ Cv, const float* __restrict__ pos, int posmode,
    int out_bf16, int N, int K) {
    __shared__ ushort As[TM * TK];   // [m][k] contiguous (lane-linear for gll)
    __shared__ ushort Bs[TN * TK];   // [n][k]

    const int t    = threadIdx.x;
    const int lane = t & 63, w = t >> 6;
    const int quad = lane >> 4, l15 = lane & 15;
    const int bm = blockIdx.x * TM, bn = blockIdx.y * TN;
    const int wm = (w & 1) * 64, wn = (w >> 1) * 64;
    const int r0 = t >> 2, kp = (t & 3) * 8;   // staging row / k-part

    f32x4 acc[4][4];
#pragma unroll
    for (int mi = 0; mi < 4; ++mi)
#pragma unroll
        for (int ni = 0; ni < 4; ++ni)
            acc[mi][ni] = (f32x4){0.f, 0.f, 0.f, 0.f};

    const ushort* Ap0 = A  + (size_t)(bm + r0) * K + kp;
    const ushort* Ap1 = A  + (size_t)(bm + 64 + r0) * K + kp;
    const ushort* Bp0 = Bt + (size_t)(bn + r0) * K + kp;
    const ushort* Bp1 = Bt + (size_t)(bn + 64 + r0) * K + kp;
    ushort* Asd0 = &As[t * 8];
    ushort* Asd1 = &As[2048 + t * 8];
    ushort* Bsd0 = &Bs[t * 8];
    ushort* Bsd1 = &Bs[2048 + t * 8];

    for (int k0 = 0; k0 < K; k0 += TK) {
        __syncthreads();
        gll16(Ap0 + k0, Asd0);
        gll16(Ap1 + k0, Asd1);
        gll16(Bp0 + k0, Bsd0);
        gll16(Bp1 + k0, Bsd1);
        __syncthreads();

        short8 af[4], bfv[4];
#pragma unroll
        for (int mi = 0; mi < 4; ++mi)
            af[mi] = *(const short8*)&As[(wm + mi * 16 + l15) * TK + quad * 8];
#pragma unroll
        for (int ni = 0; ni < 4; ++ni)
            bfv[ni] = *(const short8*)&Bs[(wn + ni * 16 + l15) * TK + quad * 8];
#pragma unroll
        for (int mi = 0; mi < 4; ++mi)
#pragma unroll
            for (int ni = 0; ni < 4; ++ni)
                acc[mi][ni] = __builtin_amdgcn_mfma_f32_16x16x32_bf16(
                    af[mi], bfv[ni], acc[mi][ni], 0, 0, 0);
    }

#pragma unroll
    for (int mi = 0; mi < 4; ++mi) {
#pragma unroll
        for (int r = 0; r < 4; ++r) {
            const int row = bm + wm + mi * 16 + quad * 4 + r;
            const int s   = row & (SEQ - 1);
#pragma unroll
            for (int ni = 0; ni < 4; ++ni) {
                const int col = bn + wn + ni * 16 + l15;
                float v = acc[mi][ni][r];
                if (posmode && col < 2048) v += pos[s * DHEAD + (col & 63)];
                if (out_bf16) ((ushort*)Cv)[(size_t)row * N + col] = bf16_1(v);
                else          ((float*) Cv)[(size_t)row * N + col] = v;
            }
        }
    }
}

// -------- MFMA flash attention, S^T form + paired tiles + reg prefetch -----
// block: q-tiles (pair, 31-pair) x one (b,h); 4 waves; wave owns 16 q-rows.
#define LDP 72   // padded LDS row stride in ushorts

__global__ __launch_bounds__(256) void attn_mfma3(
    const ushort* __restrict__ QKV, const ushort* __restrict__ Vt,
    ushort* __restrict__ AOb) {
    __shared__ ushort Ks[64 * LDP];
    __shared__ ushort Vs[64 * LDP];
    __shared__ ushort Ps[64 * LDP];

    const int pair = blockIdx.x;          // 0..15
    const int bh   = blockIdx.y;
    const int b    = bh >> 4, h = bh & 15;
    const int t    = threadIdx.x;
    const int lane = t & 63, w = t >> 6;
    const int quad = lane >> 4, l15 = lane & 15;
    const int wrow = w * 16;
    const int sr = t >> 2;                // staging row 0..63
    const int sc = (t & 3) * 16;          // 0,16,32,48
    const float SCL = 0.03125f * 1.44269504088896f;   // scale * log2(e)

    const size_t qbase = (size_t)b * SEQ * QKVS + h * 64;
    const ushort* kpb = QKV + qbase + 1024 + (size_t)sr * QKVS + sc;  // + kt*64*QKVS
    const ushort* vpb = Vt + ((size_t)bh * 64 + sr) * SEQ;            // + kt*64 + sc

#pragma unroll
    for (int ph = 0; ph < 2; ++ph) {
        const int qt = ph ? (31 - pair) : pair;

        // Q fragments directly from global (B-operand of S^T)
        const ushort* qp = QKV + qbase + (size_t)(qt * 64 + wrow + l15) * QKVS + quad * 8;
        const short8 aq0 = *(const short8*)qp;
        const short8 aq1 = *(const short8*)(qp + 32);

        // prefetch kt = 0
        uint4 ka = *(const uint4*)kpb;
        uint4 kb = *(const uint4*)(kpb + 8);
        uint4 va = *(const uint4*)(vpb + sc);
        uint4 vb = *(const uint4*)(vpb + sc + 8);

        f32x4 acc_o[4];
#pragma unroll
        for (int nd = 0; nd < 4; ++nd) acc_o[nd] = (f32x4){0.f, 0.f, 0.f, 0.f};
        float m_l = -3.0e38f, l_l = 0.f;          // softmax state for q = l15
        const int qrow_g = qt * 64 + wrow + l15;

        for (int kt = 0; kt <= qt; ++kt) {
            __syncthreads();
            *(uint4*)&Ks[sr * LDP + sc]     = ka;
            *(uint4*)&Ks[sr * LDP + sc + 8] = kb;
            *(uint4*)&Vs[sr * LDP + sc]     = va;
            *(uint4*)&Vs[sr * LDP + sc + 8] = vb;
            // prefetch next tile (overlaps this tile's compute)
            const int ktn = (kt < qt) ? kt + 1 : qt;
            ka = *(const uint4*)(kpb + (size_t)ktn * 64 * QKVS);
            kb = *(const uint4*)(kpb + (size_t)ktn * 64 * QKVS + 8);
            va = *(const uint4*)(vpb + ktn * 64 + sc);
            vb = *(const uint4*)(vpb + ktn * 64 + sc + 8);
            __syncthreads();

            // ---- S^T = K Q^T : lane holds (key=kg*16+quad*4+r, q=l15) ----
            float sv[4][4];
            float mloc = m_l;
            const bool diag = (kt == qt);
#pragma unroll
            for (int kg = 0; kg < 4; ++kg) {
                const short8 ak0 = *(const short8*)&Ks[(kg * 16 + l15) * LDP + quad * 8];
                const short8 ak1 = *(const short8*)&Ks[(kg * 16 + l15) * LDP + 32 + quad * 8];
                f32x4 a = (f32x4){0.f, 0.f, 0.f, 0.f};
                a = __builtin_amdgcn_mfma_f32_16x16x32_bf16(ak0, aq0, a, 0, 0, 0);
                a = __builtin_amdgcn_mfma_f32_16x16x32_bf16(ak1, aq1, a, 0, 0, 0);
                const int keyb = kt * 64 + kg * 16 + quad * 4;
#pragma unroll
                for (int r = 0; r < 4; ++r) {
                    float v = a[r] * SCL;                       // log2-domain
                    if (diag && (keyb + r > qrow_g)) v = -3.0e38f;
                    sv[kg][r] = v;
                    mloc = fmaxf(mloc, v);
                }
            }
            mloc = fmaxf(mloc, __shfl_xor(mloc, 16, 64));
            mloc = fmaxf(mloc, __shfl_xor(mloc, 32, 64));
            const float alpha = exp2_fast(m_l - mloc);
            m_l = mloc;
            float rs = 0.f;
#pragma unroll
            for (int kg = 0; kg < 4; ++kg)
#pragma unroll
                for (int r = 0; r < 4; ++r) {
                    float p = exp2_fast(sv[kg][r] - mloc);
                    sv[kg][r] = p;
                    rs += p;
                }
            rs += __shfl_xor(rs, 16, 64);
            rs += __shfl_xor(rs, 32, 64);
            l_l = l_l * alpha + rs;

            // broadcast alpha to accumulator layout (row q = quad*4+r)
            float av[4];
#pragma unroll
            for (int r = 0; r < 4; ++r) av[r] = __shfl(alpha, quad * 4 + r, 64);
#pragma unroll
            for (int nd = 0; nd < 4; ++nd)
#pragma unroll
                for (int r = 0; r < 4; ++r) acc_o[nd][r] *= av[r];

            // ---- P[q][key] write: 4 x b64 per lane (per-wave region) ----
#pragma unroll
            for (int kg = 0; kg < 4; ++kg) {
                uint2 u;
                u.x = pack_bf16x2(sv[kg][0], sv[kg][1]);
                u.y = pack_bf16x2(sv[kg][2], sv[kg][3]);
                *(uint2*)&Ps[(wrow + l15) * LDP + kg * 16 + quad * 4] = u;
            }
            const short8 pa0 = *(const short8*)&Ps[(wrow + l15) * LDP + quad * 8];
            const short8 pa1 = *(const short8*)&Ps[(wrow + l15) * LDP + 32 + quad * 8];
#pragma unroll
            for (int nd = 0; nd < 4; ++nd) {
                const short8 bv0 = *(const short8*)&Vs[(nd * 16 + l15) * LDP + quad * 8];
                const short8 bv1 = *(const short8*)&Vs[(nd * 16 + l15) * LDP + 32 + quad * 8];
                acc_o[nd] = __builtin_amdgcn_mfma_f32_16x16x32_bf16(pa0, bv0, acc_o[nd], 0, 0, 0);
                acc_o[nd] = __builtin_amdgcn_mfma_f32_16x16x32_bf16(pa1, bv1, acc_o[nd], 0, 0, 0);
            }
        }

        // ---- epilogue ----
        float linv[4];
#pragma unroll
        for (int r = 0; r < 4; ++r) linv[r] = 1.0f / __shfl(l_l, quad * 4 + r, 64);
#pragma unroll
        for (int nd = 0; nd < 4; ++nd)
#pragma unroll
            for (int r = 0; r < 4; ++r) {
                const int row = qt * 64 + wrow + quad * 4 + r;
                AOb[(size_t)(b * SEQ + row) * EMB + h * 64 + nd * 16 + l15] =
                    bf16_1(acc_o[nd][r] * linv[r]);
            }
    }
}

// ---------------- fp32 fallback GEMM ----------------
#define BM 64
#define BN 64
#define BK 16

__global__ __launch_bounds__(256) void gemm_f32(
    const float* __restrict__ A, const float* __restrict__ B,
    float* __restrict__ C, const float* __restrict__ pos, int addpos,
    int M, int N, int K) {
    __shared__ float As[BK][BM];
    __shared__ float Bs[BK][BN];
    const int tid = threadIdx.x;
    const int bm  = blockIdx.x * BM;
    const int bn  = blockIdx.y * BN;
    const int tx  = tid & 15;
    const int ty  = tid >> 4;
    const int arow = tid >> 2;
    const int acol = (tid & 3) << 2;
    const int brow = tid >> 4;
    const int bcol = (tid & 15) << 2;
    float acc[4][4] = {{0.f}};
    const float* Aptr = A + (size_t)(bm + arow) * K + acol;
    const float* Bptr = B + (size_t)brow * N + bn + bcol;
    for (int k0 = 0; k0 < K; k0 += BK) {
        float4 av = *(const float4*)(Aptr + k0);
        float4 bv = *(const float4*)(Bptr + (size_t)k0 * N);
        __syncthreads();
        As[acol + 0][arow] = av.x;
        As[acol + 1][arow] = av.y;
        As[acol + 2][arow] = av.z;
        As[acol + 3][arow] = av.w;
        *(float4*)&Bs[brow][bcol] = bv;
        __syncthreads();
#pragma unroll
        for (int kk = 0; kk < BK; ++kk) {
            float4 a = *(const float4*)&As[kk][ty << 2];
            float4 b = *(const float4*)&Bs[kk][tx << 2];
            float aa[4] = {a.x, a.y, a.z, a.w};
            float bb[4] = {b.x, b.y, b.z, b.w};
#pragma unroll
            for (int i = 0; i < 4; ++i)
#pragma unroll
                for (int j = 0; j < 4; ++j)
                    acc[i][j] += aa[i] * bb[j];
        }
    }
#pragma unroll
    for (int i = 0; i < 4; ++i) {
        int m = bm + (ty << 2) + i;
        int n = bn + (tx << 2);
        float4 v = make_float4(acc[i][0], acc[i][1], acc[i][2], acc[i][3]);
        if (addpos) {
            int s = m & (SEQ - 1);
            int d = n & (DHEAD - 1);
            float4 p = *(const float4*)&pos[s * DHEAD + d];
            v.x += p.x; v.y += p.y; v.z += p.z; v.w += p.w;
        }
        *(float4*)&C[(size_t)m * N + n] = v;
    }
}

// ---------------- fp32 fallback attention ----------------
#define QT 128
#define KT 32
__global__ __launch_bounds__(QT) void attn_fwd(
    const float* __restrict__ Q, const float* __restrict__ Kg,
    const float* __restrict__ V, float* __restrict__ O) {
    __shared__ float Ks[KT][DHEAD];
    __shared__ float Vs[KT][DHEAD];
    const int t    = threadIdx.x;
    const int q0   = blockIdx.x * QT;
    const int bh   = blockIdx.y;
    const int b    = bh >> 4;
    const int h    = bh & 15;
    const int qrow = q0 + t;
    const size_t base = (size_t)b * SEQ * EMB + (size_t)h * DHEAD;
    float4 q4[16], o4[16];
#pragma unroll
    for (int i = 0; i < 16; ++i) {
        q4[i] = *(const float4*)&Q[base + (size_t)qrow * EMB + i * 4];
        o4[i] = make_float4(0.f, 0.f, 0.f, 0.f);
    }
    float m_i = -3.0e38f, l_i = 0.0f;
    const float scale = 0.03125f;
    const int kend = q0 + QT;
    for (int k0 = 0; k0 < kend; k0 += KT) {
        __syncthreads();
#pragma unroll
        for (int i = 0; i < 4; ++i) {
            int idx = t + i * QT;
            int r = idx >> 4;
            int c = (idx & 15) << 2;
            *(float4*)&Ks[r][c] = *(const float4*)&Kg[base + (size_t)(k0 + r) * EMB + c];
            *(float4*)&Vs[r][c] = *(const float4*)&V [base + (size_t)(k0 + r) * EMB + c];
        }
        __syncthreads();
        float sv[KT];
        float mt = m_i;
#pragma unroll
        for (int j = 0; j < KT; ++j) {
            const float4* kr = (const float4*)Ks[j];
            float dot = 0.f;
#pragma unroll
            for (int dd = 0; dd < 16; ++dd) {
                float4 kv = kr[dd];
                dot += q4[dd].x * kv.x + q4[dd].y * kv.y +
                       q4[dd].z * kv.z + q4[dd].w * kv.w;
            }
            sv[j] = (k0 + j <= qrow) ? dot * scale : -3.0e38f;
            mt = fmaxf(mt, sv[j]);
        }
        float corr = __expf(m_i - mt);
        l_i *= corr;
#pragma unroll
        for (int i = 0; i < 16; ++i) {
            o4[i].x *= corr; o4[i].y *= corr; o4[i].z *= corr; o4[i].w *= corr;
        }
#pragma unroll
        for (int j = 0; j < KT; ++j) {
            float pp = __expf(sv[j] - mt);
            l_i += pp;
            const float4* vr = (const float4*)Vs[j];
#pragma unroll
            for (int dd = 0; dd < 16; ++dd) {
                float4 vv = vr[dd];
                o4[dd].x += pp * vv.x; o4[dd].y += pp * vv.y;
                o4[dd].z += pp * vv.z; o4[dd].w += pp * vv.w;
            }
        }
        m_i = mt;
    }
    float inv = 1.0f / l_i;
#pragma unroll
    for (int i = 0; i < 16; ++i) {
        float4 v = o4[i];
        v.x *= inv; v.y *= inv; v.z *= inv; v.w *= inv;
        *(float4*)&O[base + (size_t)qrow * EMB + i * 4] = v;
    }
}

// ---------------- launch ----------------
extern "C" void kernel_launch(void* const* d_in, const int* in_sizes, int n_in,
                              void* d_out, int out_size, void* d_ws, size_t ws_size,
                              hipStream_t stream) {
    const float* x  = (const float*)d_in[0];
    const float* Wq = (const float*)d_in[1];
    const float* Wk = (const float*)d_in[2];
    const float* Wv = (const float*)d_in[3];
    const float* Wo = (const float*)d_in[4];
    float* out = (float*)d_out;

    char* ws = (char*)d_ws;
    size_t off = 0;
    float*  pos   = (float*)(ws + off);  off += (size_t)SEQ * DHEAD * 4;
    ushort* xb    = (ushort*)(ws + off); off += (size_t)MROWS * EMB * 2;
    ushort* Wqkvt = (ushort*)(ws + off); off += (size_t)QKVS * EMB * 2;
    ushort* Wot   = (ushort*)(ws + off); off += (size_t)EMB * EMB * 2;
    ushort* QKV   = (ushort*)(ws + off); off += (size_t)MROWS * QKVS * 2;
    ushort* Vtp   = (ushort*)(ws + off); off += (size_t)MROWS * EMB * 2;
    ushort* AOb   = (ushort*)(ws + off); off += (size_t)MROWS * EMB * 2;
    const bool use_bf16 = off <= ws_size;

    const int M = MROWS, K = EMB;

    pos_init<<<SEQ, DHEAD, 0, stream>>>(pos);

    if (use_bf16) {
        const int n2 = MROWS * EMB / 2;
        cvt_bf16<<<n2 / 256, 256, 0, stream>>>(x, xb, n2);
        wt_bf16_all<<<dim3(EMB / 32, EMB / 32, 4), 256, 0, stream>>>(
            Wq, Wk, Wv, Wo, Wqkvt, Wot);

        // fused QKV projection: [4096,1024] @ [1024,3072] -> bf16 + pos
        gemm_mfma2<<<dim3(M / TM, QKVS / TN), 256, 0, stream>>>(
            xb, Wqkvt, QKV, pos, 1, 1, QKVS, K);

        vt_tr<<<dim3(SEQ / 64, BATCH * NHEAD), 256, 0, stream>>>(QKV, Vtp);

        attn_mfma3<<<dim3(16, BATCH * NHEAD), 256, 0, stream>>>(QKV, Vtp, AOb);

        gemm_mfma2<<<dim3(M / TM, EMB / TN), 256, 0, stream>>>(
            AOb, Wot, out, pos, 0, 0, EMB, K);
    } else {
        // fp32 fallback
        size_t f = 0;
        float* posf = (float*)(ws + f); f += (size_t)SEQ * DHEAD * 4;
        float* Qb = (float*)(ws + f); f += (size_t)MROWS * EMB * 4;
        float* Kb = (float*)(ws + f); f += (size_t)MROWS * EMB * 4;
        float* Vb = (float*)(ws + f); f += (size_t)MROWS * EMB * 4;
        float* AO = (float*)(ws + f);
        dim3 g(M / BM, EMB / BN);
        gemm_f32<<<g, 256, 0, stream>>>(x, Wq, Qb, posf, 1, M, EMB, K);
        gemm_f32<<<g, 256, 0, stream>>>(x, Wk, Kb, posf, 1, M, EMB, K);
        gemm_f32<<<g, 256, 0, stream>>>(x, Wv, Vb, posf, 0, M, EMB, K);
        attn_fwd<<<dim3(SEQ / QT, BATCH * NHEAD), QT, 0, stream>>>(Qb, Kb, Vb, AO);
        gemm_f32<<<g, 256, 0, stream>>>(AO, Wo, out, posf, 0, M, EMB, K);
    }
}